// Round 9
// baseline (1268.449 us; speedup 1.0000x reference)
//
#include <hip/hip_runtime.h>
#include <cstdint>
#include <cstddef>

#define NN 20000
#define EE 320000
#define FF 128
#define RR 32
#define MTE 16   // edges per msg block

typedef float  f32x4  __attribute__((ext_vector_type(4)));
typedef short  bf16x8 __attribute__((ext_vector_type(8)));

__device__ __forceinline__ float swishf(float x) {
    return x / (1.f + __expf(-x));
}
__device__ __forceinline__ unsigned short f2bf(float f) {
    unsigned int u = __builtin_bit_cast(unsigned int, f);
    u = (u + 0x7FFFu + ((u >> 16) & 1u)) >> 16;
    return (unsigned short)u;
}
__device__ __forceinline__ float bf2f(unsigned short h) {
    unsigned int u = ((unsigned int)h) << 16;
    return __builtin_bit_cast(float, u);
}

// ---------------------------------------------------------------------------
// Pass 1: active-edge degree histogram over destination i
// ---------------------------------------------------------------------------
__global__ __launch_bounds__(256) void geom_deg_kernel(
    const float* __restrict__ pos, const int* __restrict__ eidx,
    int* __restrict__ deg)
{
    int e = blockIdx.x * 256 + threadIdx.x;
    if (e >= EE) return;
    int i = eidx[e], j = eidx[EE + e];
    float dx = pos[3*j+0] - pos[3*i+0];
    float dy = pos[3*j+1] - pos[3*i+1];
    float dz = pos[3*j+2] - pos[3*i+2];
    float r = sqrtf(dx*dx + dy*dy + dz*dz + 1e-12f);
    if (r >= 0.3f && r < 5.0f) atomicAdd(&deg[i], 1);
}

// ---------------------------------------------------------------------------
// Exclusive scan: cursor (consumed by scatter) + cstart (preserved; [NN]=total)
// ---------------------------------------------------------------------------
__global__ __launch_bounds__(256) void scan_kernel(
    const int* __restrict__ deg, int* __restrict__ cursor, int* __restrict__ cstart)
{
    __shared__ int part[256];
    const int t = threadIdx.x;
    const int lo = t * 79;
    const int hi = min(lo + 79, NN);
    int s = 0;
    for (int k = lo; k < hi; k++) s += deg[k];
    part[t] = s;
    __syncthreads();
    for (int off = 1; off < 256; off <<= 1) {
        int v = (t >= off) ? part[t - off] : 0;
        __syncthreads();
        part[t] += v;
        __syncthreads();
    }
    int run = (t == 0) ? 0 : part[t - 1];
    for (int k = lo; k < hi; k++) { cursor[k] = run; cstart[k] = run; run += deg[k]; }
    if (t == 255) cstart[NN] = part[255];
}

// ---------------------------------------------------------------------------
// Nodes needing zero-init before msg: zero-degree OR edge range crosses a
// 16-edge tile boundary (those get atomicAdd partials). Layer-invariant.
// ---------------------------------------------------------------------------
__global__ __launch_bounds__(256) void clearlist_kernel(
    const int* __restrict__ cstart, int* __restrict__ list, int* __restrict__ cnt)
{
    int n = blockIdx.x * 256 + threadIdx.x;
    if (n >= NN) return;
    int s = cstart[n], t = cstart[n + 1];
    bool need = (s == t) || ((s >> 4) != ((t - 1) >> 4));
    if (need) list[atomicAdd(cnt, 1)] = n;
}

// ---------------------------------------------------------------------------
// Zero the agg rows of listed nodes (grid-stride).
// ---------------------------------------------------------------------------
__global__ __launch_bounds__(256) void clear_kernel(
    const int* __restrict__ list, const int* __restrict__ cnt,
    float* __restrict__ aggS, float* __restrict__ aggT)
{
    const int total = (*cnt) * 384;    // 12 rows * 32 float4 per node
    const f32x4 z = (f32x4){0.f, 0.f, 0.f, 0.f};
    for (int idx = blockIdx.x * 256 + threadIdx.x; idx < total; idx += gridDim.x * 256) {
        int ni = idx / 384, rem = idx - ni * 384;
        int n = list[ni];
        if (rem < 32) *(f32x4*)&aggS[((size_t)n << 7) + rem * 4] = z;
        else {
            int r = rem - 32;
            *(f32x4*)&aggT[(((size_t)n * 11 + (r >> 5)) << 7) + (r & 31) * 4] = z;
        }
    }
}

// ---------------------------------------------------------------------------
// Pass 2: recompute geometry, scatter active edges into i-sorted slots.
// ---------------------------------------------------------------------------
__global__ __launch_bounds__(256) void geom_scatter_kernel(
    const float* __restrict__ pos, const int* __restrict__ eidx,
    const float* __restrict__ freq, int* __restrict__ cursor,
    int* __restrict__ ei, int* __restrict__ ej,
    float* __restrict__ sh, unsigned short* __restrict__ rbfq)
{
    int e = blockIdx.x * 256 + threadIdx.x;
    if (e >= EE) return;
    int i = eidx[e], j = eidx[EE + e];
    float dx = pos[3*j+0] - pos[3*i+0];
    float dy = pos[3*j+1] - pos[3*i+1];
    float dz = pos[3*j+2] - pos[3*i+2];
    float r = sqrtf(dx*dx + dy*dy + dz*dz + 1e-12f);
    if (!(r >= 0.3f && r < 5.0f)) return;
    int slot = atomicAdd(&cursor[i], 1);
    ei[slot] = i; ej[slot] = j;
    float ir = 1.f / (r + 1e-6f);
    float x = dx*ir, y = dy*ir, z = dz*ir;
    const float s3 = 1.7320508075688772f, s5 = 2.23606797749979f, s15 = 3.872983346207417f;
    float* shp = sh + (size_t)slot * 8;
    shp[0] = s3*y; shp[1] = s3*z; shp[2] = s3*x;
    shp[3] = s15*x*y; shp[4] = s15*y*z; shp[5] = 0.5f*s5*(3.f*z*z - 1.f);
    shp[6] = s15*z*x; shp[7] = 0.5f*s15*(x*x - y*y);
    float fc = 0.5f * (cosf(3.14159265358979323846f * r * 0.2f) + 1.f);
    float pref = 0.6324555320336759f * fc * ir;
    unsigned short* rp = rbfq + (size_t)slot * RR;
    for (int k = 0; k < RR; k++) rp[k] = f2bf(pref * sinf(freq[k] * r * 0.2f));
}

// ---------------------------------------------------------------------------
// S = swish(emb_table[z] @ emb_W + emb_b)
// ---------------------------------------------------------------------------
__global__ __launch_bounds__(128) void embed_kernel(
    const int* __restrict__ z, const float* __restrict__ emb_table,
    const float* __restrict__ emb_W, const float* __restrict__ emb_b,
    float* __restrict__ S)
{
    int n = blockIdx.x;
    int f = threadIdx.x;
    __shared__ float row[FF];
    row[f] = emb_table[(size_t)z[n]*FF + f];
    __syncthreads();
    float acc = emb_b[f];
    for (int k = 0; k < FF; k++) acc += row[k] * emb_W[k*FF + f];
    S[(size_t)n*FF + f] = swishf(acc);
}

// ---------------------------------------------------------------------------
// Node-weight pack (hi/lo split): W1o@0, W1e@16384, W2e@32768, Wup@49152;
// per-layer stride 114688 elems.
// ---------------------------------------------------------------------------
__global__ __launch_bounds__(256) void pack_kernel(
    const float* __restrict__ W1o, const float* __restrict__ W1e,
    const float* __restrict__ W2e, const float* __restrict__ Wup,
    unsigned short* __restrict__ ph, unsigned short* __restrict__ pl)
{
    int t = blockIdx.x * 256 + threadIdx.x;
    if (t >= 3 * 14336) return;
    int b = t / 14336, r = t % 14336;
    const float* src; int nks; size_t dstoff;
    if (r < 6144) {
        int mat = r / 2048, rr = r % 2048;
        src = (mat == 0 ? W1o : mat == 1 ? W1e : W2e) + (size_t)b * 16384;
        nks = 4;
        dstoff = (size_t)b * 114688 + (size_t)mat * 16384 + (size_t)rr * 8;
        r = rr;
    } else {
        int rr = r - 6144;
        src = Wup + (size_t)b * 65536;
        nks = 16;
        dstoff = (size_t)b * 114688 + 49152 + (size_t)rr * 8;
        r = rr;
    }
    int lane = r & 63;
    int fi = r >> 6;
    int ks = fi % nks, ct = fi / nks;
    int col = ct * 16 + (lane & 15);
    int kb = ks * 32 + (lane >> 4) * 8;
    #pragma unroll
    for (int e = 0; e < 8; e++) {
        float v = src[(size_t)(kb + e) * 128 + col];
        unsigned short h = f2bf(v);
        ph[dstoff + e] = h;
        pl[dstoff + e] = f2bf(v - bf2f(h));
    }
}

// ---------------------------------------------------------------------------
// Pack [Wsrc | Wu] (K=128, N=512) into bf16 B-frags.
// ---------------------------------------------------------------------------
__global__ __launch_bounds__(256) void pack_pu_kernel(
    const float* __restrict__ Wsrc, const float* __restrict__ Wu,
    unsigned short* __restrict__ packPU)
{
    int t = blockIdx.x * 256 + threadIdx.x;
    if (t >= 3 * 8192) return;
    int b = t / 8192, r = t % 8192;
    int lane = r & 63, fi = r >> 6;       // fi = ct*4+ks
    int ks = fi & 3, ct = fi >> 2;
    int kb = ks * 32 + (lane >> 4) * 8;
    int colq = lane & 15;
    const float* src; int col, stride;
    if (ct < 8) { src = Wsrc + (size_t)b * 16384; col = ct*16 + colq; stride = 128; }
    else        { src = Wu   + (size_t)b * 49152; col = (ct-8)*16 + colq; stride = 384; }
    size_t dst = (size_t)b * 65536 + (size_t)fi * 512 + (size_t)lane * 8;
    #pragma unroll
    for (int e = 0; e < 8; e++)
        packPU[dst + e] = f2bf(src[(size_t)(kb + e) * stride + col]);
}

// ---------------------------------------------------------------------------
// Pack Wf2 (K=128, N=512) into bf16 B-frags.
// ---------------------------------------------------------------------------
__global__ __launch_bounds__(256) void pack_f2_kernel(
    const float* __restrict__ Wf2, unsigned short* __restrict__ packF2)
{
    int t = blockIdx.x * 256 + threadIdx.x;
    if (t >= 3 * 8192) return;
    int b = t / 8192, r = t % 8192;
    int lane = r & 63, fi = r >> 6;
    int ks = fi & 3, ct = fi >> 2;
    int kb = ks * 32 + (lane >> 4) * 8;
    int col = ct * 16 + (lane & 15);
    const float* src = Wf2 + (size_t)b * 65536;
    size_t dst = (size_t)b * 65536 + (size_t)fi * 512 + (size_t)lane * 8;
    #pragma unroll
    for (int e = 0; e < 8; e++)
        packF2[dst + e] = f2bf(src[(size_t)(kb + e) * 512 + col]);
}

// ---------------------------------------------------------------------------
// Standalone projection (layer 0 only): PU = [swish(S@Wsrc) | S@Wu], MFMA.
// INTERLEAVED output: PU[n*512 + f*4 + c], c in {0:P,1:U1,2:U2,3:U3}.
// ---------------------------------------------------------------------------
__global__ __launch_bounds__(256) void proj_kernel(
    const float* __restrict__ S, const unsigned short* __restrict__ packPU,
    unsigned short* __restrict__ PU)
{
    __shared__ float stage[16][132];
    const int tid = threadIdx.x;
    const int n0 = blockIdx.x * 16;

    for (int idx = tid; idx < 512; idx += 256) {
        int row = idx >> 5, k4 = (idx & 31) << 2;
        *(float4*)&stage[row][k4] = *(const float4*)&S[((size_t)(n0 + row) << 7) + k4];
    }
    __syncthreads();

    const int lane = tid & 63;
    const int wid  = tid >> 6;
    const int row  = lane & 15;
    const int k0   = (lane >> 4) * 8;

    f32x4 acc[8];
    #pragma unroll
    for (int c = 0; c < 8; c++) acc[c] = (f32x4){0.f, 0.f, 0.f, 0.f};

    #pragma unroll
    for (int ks = 0; ks < 4; ks++) {
        const float* sp = &stage[row][ks*32 + k0];
        bf16x8 a;
        #pragma unroll
        for (int e = 0; e < 8; e++) a[e] = (short)f2bf(sp[e]);
        #pragma unroll
        for (int cti = 0; cti < 8; cti++) {
            int ct = wid * 8 + cti;
            bf16x8 b = *(const bf16x8*)(packPU + (((size_t)ct * 4 + ks) * 64 + lane) * 8);
            acc[cti] = __builtin_amdgcn_mfma_f32_16x16x32_bf16(a, b, acc[cti], 0, 0, 0);
        }
    }

    #pragma unroll
    for (int cti = 0; cti < 8; cti++) {
        int ct = wid * 8 + cti;
        int cblk = ct >> 3;
        int fcol = (ct & 7) * 16 + (lane & 15);
        #pragma unroll
        for (int q = 0; q < 4; q++) {
            int n = n0 + (lane >> 4) * 4 + q;
            float v = acc[cti][q];
            if (cblk == 0) v = swishf(v);
            PU[(size_t)n * 512 + fcol * 4 + cblk] = f2bf(v);
        }
    }
}

// ---------------------------------------------------------------------------
// Message kernel: R8 + batch PU prefetch. 16 i-sorted edges/block.
//  h (VALU) -> w (MFMA, channel-interleaved LDS) -> PREFETCH all 16 PU
//  gathers into registers (single memory round trip) -> formation; flush at
//  i-transitions (interior: plain store, boundary: atomicAdd).
// ---------------------------------------------------------------------------
__global__ __launch_bounds__(256) void msg_kernel(
    const int* __restrict__ cstart,
    const int* __restrict__ ei, const int* __restrict__ ej,
    const float* __restrict__ sh, const unsigned short* __restrict__ rbfq,
    const float* __restrict__ Wf1, const float* __restrict__ bf1,
    const unsigned short* __restrict__ packF2, const unsigned short* __restrict__ PU,
    float* __restrict__ aggS, float* __restrict__ aggT)
{
    const int Ea = cstart[NN];
    const int base = blockIdx.x * MTE;
    if (base >= Ea) return;
    const int nval = min(MTE, Ea - base);
    const int tid = threadIdx.x;
    const int f = tid & 127;
    const int half = tid >> 7;
    const int lane = tid & 63;
    const int wid  = tid >> 6;

    __shared__ float          rbf_s[MTE][RR];
    __shared__ unsigned short h_s[MTE][FF];
    __shared__ unsigned short w_s[MTE][520];   // interleaved [fcol*4+cblk]
    __shared__ float          sh_s[MTE][8];
    __shared__ int            i_s[MTE], j_s[MTE];

    if (tid < MTE) {
        i_s[tid] = (tid < nval) ? ei[base + tid] : -1;
        j_s[tid] = (tid < nval) ? ej[base + tid] : 0;
    }
    if (tid >= 64 && tid < 64 + MTE*8) {
        int t = tid - 64, e = t >> 3;
        sh_s[e][t & 7] = (e < nval) ? sh[(size_t)(base + e)*8 + (t & 7)] : 0.f;
    }
    for (int t = tid; t < MTE*RR; t += 256) {
        int e = t >> 5, k = t & 31;
        rbf_s[e][k] = (e < nval) ? bf2f(rbfq[(size_t)(base + e)*RR + k]) : 0.f;
    }
    __syncthreads();

    // h = swish(rbf @ Wf1 + bf1): thread (f,half) does edges half*8..+8
    {
        float hacc[8];
        float bb = bf1[f];
        #pragma unroll
        for (int k = 0; k < 8; k++) hacc[k] = bb;
        for (int r = 0; r < RR; r++) {
            float wv = Wf1[r*FF + f];
            #pragma unroll
            for (int k = 0; k < 8; k++) hacc[k] += rbf_s[half*8 + k][r] * wv;
        }
        #pragma unroll
        for (int k = 0; k < 8; k++)
            h_s[half*8 + k][f] = f2bf(swishf(hacc[k]));
    }
    __syncthreads();

    // w = h @ Wf2 (MFMA); interleaved store
    {
        const int ra = lane & 15, k0 = (lane >> 4) * 8;
        f32x4 wacc[8];
        #pragma unroll
        for (int c = 0; c < 8; c++) wacc[c] = (f32x4){0.f, 0.f, 0.f, 0.f};
        #pragma unroll
        for (int ks = 0; ks < 4; ks++) {
            bf16x8 a = *(const bf16x8*)&h_s[ra][ks*32 + k0];
            #pragma unroll
            for (int cti = 0; cti < 8; cti++) {
                int ct = wid * 8 + cti;
                bf16x8 b = *(const bf16x8*)(packF2 + (((size_t)ct * 4 + ks) * 64 + lane) * 8);
                wacc[cti] = __builtin_amdgcn_mfma_f32_16x16x32_bf16(a, b, wacc[cti], 0, 0, 0);
            }
        }
        #pragma unroll
        for (int cti = 0; cti < 8; cti++) {
            int ct = wid * 8 + cti;
            int cblk = ct >> 3;
            int fcol = (ct & 7) * 16 + (lane & 15);
            #pragma unroll
            for (int q = 0; q < 4; q++)
                w_s[(lane >> 4)*4 + q][fcol*4 + cblk] = f2bf(wacc[cti][q]);
        }
    }
    __syncthreads();

    // batch-prefetch ALL 16 PU gathers (j_s padded with 0 -> safe address);
    // one memory round trip instead of 16 serialized ones.
    uint2 puv[MTE];
    #pragma unroll
    for (int e = 0; e < MTE; e++)
        puv[e] = *(const uint2*)(PU + ((size_t)j_s[e] << 9) + (f << 2));
    __builtin_amdgcn_sched_barrier(0);   // keep loads issued before the loop

    // formation: flush at i-transitions (hybrid store/atomic)
    float aS=0.f, a3=0.f, a4=0.f, a5=0.f;                            // half 0
    float a0=0.f,a1=0.f,a2=0.f,a6=0.f,a7=0.f,a8=0.f,a9=0.f,a10=0.f;  // half 1
    int cur = i_s[0];

    auto flush = [&](int node) {
        bool interior = (cstart[node] >= base) && (cstart[node + 1] <= base + nval);
        if (half == 0) {
            size_t sA = ((size_t)node << 7) + f;
            size_t bT = (((size_t)node*11 + 3) << 7) + f;
            if (interior) {
                aggS[sA] = aS;
                aggT[bT] = a3; aggT[bT + 128] = a4; aggT[bT + 256] = a5;
            } else {
                atomicAdd(&aggS[sA], aS);
                atomicAdd(&aggT[bT], a3); atomicAdd(&aggT[bT + 128], a4); atomicAdd(&aggT[bT + 256], a5);
            }
            aS = a3 = a4 = a5 = 0.f;
        } else {
            size_t bT  = (((size_t)node*11) << 7) + f;
            size_t bT2 = (((size_t)node*11 + 6) << 7) + f;
            if (interior) {
                aggT[bT] = a0; aggT[bT + 128] = a1; aggT[bT + 256] = a2;
                aggT[bT2] = a6; aggT[bT2 + 128] = a7; aggT[bT2 + 256] = a8;
                aggT[bT2 + 384] = a9; aggT[bT2 + 512] = a10;
            } else {
                atomicAdd(&aggT[bT], a0); atomicAdd(&aggT[bT + 128], a1); atomicAdd(&aggT[bT + 256], a2);
                atomicAdd(&aggT[bT2], a6); atomicAdd(&aggT[bT2 + 128], a7); atomicAdd(&aggT[bT2 + 256], a8);
                atomicAdd(&aggT[bT2 + 384], a9); atomicAdd(&aggT[bT2 + 512], a10);
            }
            a0=a1=a2=a6=a7=a8=a9=a10=0.f;
        }
    };

    #pragma unroll
    for (int e = 0; e < MTE; e++) {
        if (e >= nval) break;
        int ie = i_s[e];
        if (ie != cur) { flush(cur); cur = ie; }
        uint2 wv2 = *(const uint2*)&w_s[e][f*4];
        uint2 pv  = puv[e];
        if (half == 0) {
            float wS = bf2f((unsigned short)(wv2.x & 0xffff));
            float w2 = bf2f((unsigned short)(wv2.y & 0xffff));
            float P  = bf2f((unsigned short)(pv.x  & 0xffff));
            float U2 = bf2f((unsigned short)(pv.y  & 0xffff));
            aS += wS * P;
            float v = w2 * U2;
            a3 += sh_s[e][0]*v; a4 += sh_s[e][1]*v; a5 += sh_s[e][2]*v;
        } else {
            float w1 = bf2f((unsigned short)(wv2.x >> 16));
            float w3 = bf2f((unsigned short)(wv2.y >> 16));
            float U1 = bf2f((unsigned short)(pv.x  >> 16));
            float U3 = bf2f((unsigned short)(pv.y  >> 16));
            float v1 = w1 * U1;
            a0 += sh_s[e][0]*v1; a1 += sh_s[e][1]*v1; a2 += sh_s[e][2]*v1;
            float v3 = w3 * U3;
            a6 += sh_s[e][3]*v3; a7 += sh_s[e][4]*v3; a8 += sh_s[e][5]*v3;
            a9 += sh_s[e][6]*v3; a10 += sh_s[e][7]*v3;
        }
    }
    flush(cur);
}

// ---------------------------------------------------------------------------
// T-GEMM via MFMA (bf16 hi/lo split) — R3 version (validated fast).
// ---------------------------------------------------------------------------
template<int GSIZE>
__global__ __launch_bounds__(256) void tgemm_kernel(
    const float* __restrict__ aggT,
    const unsigned short* __restrict__ Wh, const unsigned short* __restrict__ Wl,
    float* __restrict__ T, float* __restrict__ inv,
    int goff, int invoff, int addT)
{
    __shared__ float stage[GSIZE][16][132];
    const int tid = threadIdx.x;
    const int n0 = blockIdx.x * 16;

    const int total = GSIZE * 16 * 32;
    for (int idx = tid; idx < total; idx += 256) {
        int mg  = idx >> 9;
        int rem = idx & 511;
        int row = rem >> 5;
        int k4  = (rem & 31) << 2;
        size_t g = (((size_t)(n0 + row) * 11 + goff + mg) << 7) + k4;
        float4 v = *(const float4*)&aggT[g];
        if (addT) {
            float4 tv = *(const float4*)&T[g];
            v.x += tv.x; v.y += tv.y; v.z += tv.z; v.w += tv.w;
        }
        *(float4*)&stage[mg][row][k4] = v;
    }
    __syncthreads();

    const int lane = tid & 63;
    const int wid  = tid >> 6;
    const int row  = lane & 15;
    const int k0   = (lane >> 4) * 8;

    f32x4 acc[GSIZE][2];
    #pragma unroll
    for (int mg = 0; mg < GSIZE; mg++) {
        acc[mg][0] = (f32x4){0.f, 0.f, 0.f, 0.f};
        acc[mg][1] = (f32x4){0.f, 0.f, 0.f, 0.f};
    }

    #pragma unroll
    for (int ks = 0; ks < 4; ks++) {
        bf16x8 ah[GSIZE], al[GSIZE];
        #pragma unroll
        for (int mg = 0; mg < GSIZE; mg++) {
            const float* sp = &stage[mg][row][ks*32 + k0];
            float v0[4], v1[4];
            *(float4*)v0 = *(const float4*)sp;
            *(float4*)v1 = *(const float4*)(sp + 4);
            #pragma unroll
            for (int e = 0; e < 4; e++) {
                unsigned short h0 = f2bf(v0[e]);
                ah[mg][e]   = (short)h0;
                al[mg][e]   = (short)f2bf(v0[e] - bf2f(h0));
                unsigned short h1 = f2bf(v1[e]);
                ah[mg][4+e] = (short)h1;
                al[mg][4+e] = (short)f2bf(v1[e] - bf2f(h1));
            }
        }
        #pragma unroll
        for (int cti = 0; cti < 2; cti++) {
            const int ct = wid * 2 + cti;
            size_t boff = (((size_t)ct * 4 + ks) * 64 + lane) * 8;
            bf16x8 bh = *(const bf16x8*)(Wh + boff);
            bf16x8 bl = *(const bf16x8*)(Wl + boff);
            #pragma unroll
            for (int mg = 0; mg < GSIZE; mg++) {
                acc[mg][cti] = __builtin_amdgcn_mfma_f32_16x16x32_bf16(ah[mg], bh, acc[mg][cti], 0, 0, 0);
                acc[mg][cti] = __builtin_amdgcn_mfma_f32_16x16x32_bf16(al[mg], bh, acc[mg][cti], 0, 0, 0);
                acc[mg][cti] = __builtin_amdgcn_mfma_f32_16x16x32_bf16(ah[mg], bl, acc[mg][cti], 0, 0, 0);
            }
        }
    }

    #pragma unroll
    for (int cti = 0; cti < 2; cti++) {
        const int ct = wid * 2 + cti;
        const int fc = ct * 16 + (lane & 15);
        #pragma unroll
        for (int q = 0; q < 4; q++) {
            const int n = n0 + (lane >> 4) * 4 + q;
            float iv = 0.f;
            #pragma unroll
            for (int mg = 0; mg < GSIZE; mg++) {
                float o = acc[mg][cti][q];
                T[(((size_t)n * 11 + goff + mg) << 7) + fc] = o;
                iv += o * o;
            }
            inv[(size_t)n * 384 + invoff + fc] = iv;
        }
    }
}

// ---------------------------------------------------------------------------
// S += swish([aggS | inv] @ Wup) + fused next-layer PU projection
// (both parts numerically validated in earlier rounds).
// ---------------------------------------------------------------------------
__global__ __launch_bounds__(256) void sgemm2_kernel(
    const float* __restrict__ aggS, const float* __restrict__ inv,
    const unsigned short* __restrict__ Wh, const unsigned short* __restrict__ Wl,
    const unsigned short* __restrict__ packPUn,
    float* __restrict__ S, unsigned short* __restrict__ PU, int doPU)
{
    __shared__ float stage[16][516];
    __shared__ float snew[16][132];
    const int tid = threadIdx.x;
    const int n0 = blockIdx.x * 16;

    for (int idx = tid; idx < 16 * 128; idx += 256) {
        int row = idx >> 7;
        int k4  = (idx & 127) << 2;
        float4 v;
        if (k4 < 128) v = *(const float4*)&aggS[((size_t)(n0 + row) << 7) + k4];
        else          v = *(const float4*)&inv[(size_t)(n0 + row) * 384 + (k4 - 128)];
        *(float4*)&stage[row][k4] = v;
    }
    __syncthreads();

    const int lane = tid & 63;
    const int wid  = tid >> 6;
    const int row  = lane & 15;
    const int k0   = (lane >> 4) * 8;

    f32x4 acc[2];
    acc[0] = (f32x4){0.f, 0.f, 0.f, 0.f};
    acc[1] = (f32x4){0.f, 0.f, 0.f, 0.f};

    for (int ks = 0; ks < 16; ks++) {
        const float* sp = &stage[row][ks*32 + k0];
        float v0[4], v1[4];
        *(float4*)v0 = *(const float4*)sp;
        *(float4*)v1 = *(const float4*)(sp + 4);
        bf16x8 ah, al;
        #pragma unroll
        for (int e = 0; e < 4; e++) {
            unsigned short h0 = f2bf(v0[e]);
            ah[e]   = (short)h0;
            al[e]   = (short)f2bf(v0[e] - bf2f(h0));
            unsigned short h1 = f2bf(v1[e]);
            ah[4+e] = (short)h1;
            al[4+e] = (short)f2bf(v1[e] - bf2f(h1));
        }
        #pragma unroll
        for (int cti = 0; cti < 2; cti++) {
            const int ct = wid * 2 + cti;
            size_t boff = (((size_t)ct * 16 + ks) * 64 + lane) * 8;
            bf16x8 bh = *(const bf16x8*)(Wh + boff);
            bf16x8 bl = *(const bf16x8*)(Wl + boff);
            acc[cti] = __builtin_amdgcn_mfma_f32_16x16x32_bf16(ah, bh, acc[cti], 0, 0, 0);
            acc[cti] = __builtin_amdgcn_mfma_f32_16x16x32_bf16(al, bh, acc[cti], 0, 0, 0);
            acc[cti] = __builtin_amdgcn_mfma_f32_16x16x32_bf16(ah, bl, acc[cti], 0, 0, 0);
        }
    }

    #pragma unroll
    for (int cti = 0; cti < 2; cti++) {
        const int ct = wid * 2 + cti;
        const int fc = ct * 16 + (lane & 15);
        #pragma unroll
        for (int q = 0; q < 4; q++) {
            const int n = n0 + (lane >> 4) * 4 + q;
            size_t o = ((size_t)n << 7) + fc;
            float sv = S[o] + swishf(acc[cti][q]);
            S[o] = sv;
            snew[(lane >> 4)*4 + q][fc] = sv;
        }
    }

    if (!doPU) return;
    __syncthreads();

    // PU(next) = [swish(S@Wsrc) | S@Wu], interleaved
    {
        f32x4 pacc[8];
        #pragma unroll
        for (int c = 0; c < 8; c++) pacc[c] = (f32x4){0.f, 0.f, 0.f, 0.f};
        #pragma unroll
        for (int ks = 0; ks < 4; ks++) {
            bf16x8 a;
            #pragma unroll
            for (int e = 0; e < 8; e++)
                a[e] = (short)f2bf(snew[row][ks*32 + k0 + e]);
            #pragma unroll
            for (int cti = 0; cti < 8; cti++) {
                int ct = wid * 8 + cti;
                bf16x8 b = *(const bf16x8*)(packPUn + (((size_t)ct * 4 + ks) * 64 + lane) * 8);
                pacc[cti] = __builtin_amdgcn_mfma_f32_16x16x32_bf16(a, b, pacc[cti], 0, 0, 0);
            }
        }
        #pragma unroll
        for (int cti = 0; cti < 8; cti++) {
            int ct = wid * 8 + cti;
            int cblk = ct >> 3;
            int fcol = (ct & 7) * 16 + (lane & 15);
            #pragma unroll
            for (int q = 0; q < 4; q++) {
                int n = n0 + (lane >> 4) * 4 + q;
                float v = pacc[cti][q];
                if (cblk == 0) v = swishf(v);
                PU[((size_t)n << 9) + fcol*4 + cblk] = f2bf(v);
            }
        }
    }
}

// ---------------------------------------------------------------------------
extern "C" void kernel_launch(void* const* d_in, const int* in_sizes, int n_in,
                              void* d_out, int out_size, void* d_ws, size_t ws_size,
                              hipStream_t stream)
{
    const int*   z         = (const int*)  d_in[0];
    const float* pos       = (const float*)d_in[1];
    const int*   eidx      = (const int*)  d_in[2];
    const float* emb_table = (const float*)d_in[3];
    const float* emb_W     = (const float*)d_in[4];
    const float* emb_b     = (const float*)d_in[5];
    const float* freq      = (const float*)d_in[6];
    const float* Wf1       = (const float*)d_in[7];
    const float* bf1       = (const float*)d_in[8];
    const float* Wf2       = (const float*)d_in[9];
    const float* Wsrc      = (const float*)d_in[10];
    const float* Wu        = (const float*)d_in[11];
    const float* W1o       = (const float*)d_in[12];
    const float* W1e       = (const float*)d_in[13];
    const float* W2e       = (const float*)d_in[14];
    const float* Wup       = (const float*)d_in[15];

    float* S = (float*)d_out;                  // (N,F)
    float* T = S + (size_t)NN*FF;              // (N,11,F)

    char* w = (char*)d_ws;
    int*   deg     = (int*)w;                     w += (size_t)NN*4 + 128;
    int*   cursor  = (int*)w;                     w += (size_t)NN*4 + 128;
    int*   cstart  = (int*)w;                     w += (size_t)(NN+1)*4 + 124;
    int*   clearcnt= (int*)w;                     w += 128;
    int*   clearlist=(int*)w;                     w += (size_t)NN*4 + 128;
    int*   ei      = (int*)w;                     w += (size_t)EE*4;
    int*   ej      = (int*)w;                     w += (size_t)EE*4;
    float* sh      = (float*)w;                   w += (size_t)EE*8*4;
    unsigned short* rbfq = (unsigned short*)w;    w += (size_t)EE*RR*2;
    unsigned short* PU   = (unsigned short*)w;    w += (size_t)NN*512*2;
    float* aggS    = (float*)w;                   w += (size_t)NN*FF*4;
    float* aggT    = (float*)w;                   w += (size_t)NN*11*FF*4;
    float* inv     = (float*)w;                   w += (size_t)NN*384*4;
    unsigned short* packH  = (unsigned short*)w;  w += (size_t)344064*2;
    unsigned short* packL  = (unsigned short*)w;  w += (size_t)344064*2;
    unsigned short* packPU = (unsigned short*)w;  w += (size_t)3*65536*2;
    unsigned short* packF2 = (unsigned short*)w;  w += (size_t)3*65536*2;

    hipMemsetAsync(deg, 0, (size_t)NN*4, stream);
    hipMemsetAsync(clearcnt, 0, 4, stream);

    geom_deg_kernel<<<(EE + 255)/256, 256, 0, stream>>>(pos, eidx, deg);
    scan_kernel<<<1, 256, 0, stream>>>(deg, cursor, cstart);
    clearlist_kernel<<<(NN + 255)/256, 256, 0, stream>>>(cstart, clearlist, clearcnt);
    geom_scatter_kernel<<<(EE + 255)/256, 256, 0, stream>>>(pos, eidx, freq, cursor, ei, ej, sh, rbfq);
    embed_kernel<<<NN, 128, 0, stream>>>(z, emb_table, emb_W, emb_b, S);
    pack_kernel<<<(3*14336 + 255)/256, 256, 0, stream>>>(W1o, W1e, W2e, Wup, packH, packL);
    pack_pu_kernel<<<(3*8192 + 255)/256, 256, 0, stream>>>(Wsrc, Wu, packPU);
    pack_f2_kernel<<<(3*8192 + 255)/256, 256, 0, stream>>>(Wf2, packF2);

    proj_kernel<<<NN/16, 256, 0, stream>>>(S, packPU, PU);   // layer-0 PU

    for (int b = 0; b < 3; b++) {
        clear_kernel<<<2048, 256, 0, stream>>>(clearlist, clearcnt, aggS, aggT);
        msg_kernel<<<(EE + MTE - 1)/MTE, 256, 0, stream>>>(
            cstart, ei, ej, sh, rbfq,
            Wf1 + (size_t)b*RR*FF, bf1 + (size_t)b*FF,
            packF2 + (size_t)b*65536, PU, aggS, aggT);

        const unsigned short* H = packH + (size_t)b*114688;
        const unsigned short* L = packL + (size_t)b*114688;
        tgemm_kernel<3><<<NN/16, 256, 0, stream>>>(aggT, H +     0, L +     0, T, inv, 0,   0, b > 0);
        tgemm_kernel<3><<<NN/16, 256, 0, stream>>>(aggT, H + 16384, L + 16384, T, inv, 3, 128, b > 0);
        tgemm_kernel<5><<<NN/16, 256, 0, stream>>>(aggT, H + 32768, L + 32768, T, inv, 6, 256, b > 0);
        sgemm2_kernel<<<NN/16, 256, 0, stream>>>(
            aggS, inv, H + 49152, L + 49152,
            packPU + (size_t)(b < 2 ? (b+1)*65536 : 0),
            S, PU, b < 2);
    }
}

// Round 10
// 1180.624 us; speedup vs baseline: 1.0744x; 1.0744x over previous
//
#include <hip/hip_runtime.h>
#include <cstdint>
#include <cstddef>

#define NN 20000
#define EE 320000
#define FF 128
#define RR 32
#define MTE 16        // edges per form block
#define WCAP 131072   // max active edges (actual Ea ~ 90k, deterministic)

typedef float  f32x4  __attribute__((ext_vector_type(4)));
typedef short  bf16x8 __attribute__((ext_vector_type(8)));

__device__ __forceinline__ float swishf(float x) {
    return x / (1.f + __expf(-x));
}
__device__ __forceinline__ unsigned short f2bf(float f) {
    unsigned int u = __builtin_bit_cast(unsigned int, f);
    u = (u + 0x7FFFu + ((u >> 16) & 1u)) >> 16;
    return (unsigned short)u;
}
__device__ __forceinline__ float bf2f(unsigned short h) {
    unsigned int u = ((unsigned int)h) << 16;
    return __builtin_bit_cast(float, u);
}

// ---------------------------------------------------------------------------
// Pass 1: active-edge degree histogram over destination i
// ---------------------------------------------------------------------------
__global__ __launch_bounds__(256) void geom_deg_kernel(
    const float* __restrict__ pos, const int* __restrict__ eidx,
    int* __restrict__ deg)
{
    int e = blockIdx.x * 256 + threadIdx.x;
    if (e >= EE) return;
    int i = eidx[e], j = eidx[EE + e];
    float dx = pos[3*j+0] - pos[3*i+0];
    float dy = pos[3*j+1] - pos[3*i+1];
    float dz = pos[3*j+2] - pos[3*i+2];
    float r = sqrtf(dx*dx + dy*dy + dz*dz + 1e-12f);
    if (r >= 0.3f && r < 5.0f) atomicAdd(&deg[i], 1);
}

// ---------------------------------------------------------------------------
// Exclusive scan: cursor (consumed by scatter) + cstart (preserved; [NN]=total)
// ---------------------------------------------------------------------------
__global__ __launch_bounds__(256) void scan_kernel(
    const int* __restrict__ deg, int* __restrict__ cursor, int* __restrict__ cstart)
{
    __shared__ int part[256];
    const int t = threadIdx.x;
    const int lo = t * 79;
    const int hi = min(lo + 79, NN);
    int s = 0;
    for (int k = lo; k < hi; k++) s += deg[k];
    part[t] = s;
    __syncthreads();
    for (int off = 1; off < 256; off <<= 1) {
        int v = (t >= off) ? part[t - off] : 0;
        __syncthreads();
        part[t] += v;
        __syncthreads();
    }
    int run = (t == 0) ? 0 : part[t - 1];
    for (int k = lo; k < hi; k++) { cursor[k] = run; cstart[k] = run; run += deg[k]; }
    if (t == 255) cstart[NN] = part[255];
}

// ---------------------------------------------------------------------------
// Nodes needing zero-init before form: zero-degree OR tile-boundary crossers.
// ---------------------------------------------------------------------------
__global__ __launch_bounds__(256) void clearlist_kernel(
    const int* __restrict__ cstart, int* __restrict__ list, int* __restrict__ cnt)
{
    int n = blockIdx.x * 256 + threadIdx.x;
    if (n >= NN) return;
    int s = cstart[n], t = cstart[n + 1];
    bool need = (s == t) || ((s >> 4) != ((t - 1) >> 4));
    if (need) list[atomicAdd(cnt, 1)] = n;
}

// ---------------------------------------------------------------------------
// Zero the agg rows of listed nodes (grid-stride).
// ---------------------------------------------------------------------------
__global__ __launch_bounds__(256) void clear_kernel(
    const int* __restrict__ list, const int* __restrict__ cnt,
    float* __restrict__ aggS, float* __restrict__ aggT)
{
    const int total = (*cnt) * 384;    // 12 rows * 32 float4 per node
    const f32x4 z = (f32x4){0.f, 0.f, 0.f, 0.f};
    for (int idx = blockIdx.x * 256 + threadIdx.x; idx < total; idx += gridDim.x * 256) {
        int ni = idx / 384, rem = idx - ni * 384;
        int n = list[ni];
        if (rem < 32) *(f32x4*)&aggS[((size_t)n << 7) + rem * 4] = z;
        else {
            int r = rem - 32;
            *(f32x4*)&aggT[(((size_t)n * 11 + (r >> 5)) << 7) + (r & 31) * 4] = z;
        }
    }
}

// ---------------------------------------------------------------------------
// Pass 2: recompute geometry, scatter active edges into i-sorted slots.
// ---------------------------------------------------------------------------
__global__ __launch_bounds__(256) void geom_scatter_kernel(
    const float* __restrict__ pos, const int* __restrict__ eidx,
    const float* __restrict__ freq, int* __restrict__ cursor,
    int* __restrict__ ei, int* __restrict__ ej,
    float* __restrict__ sh, unsigned short* __restrict__ rbfq)
{
    int e = blockIdx.x * 256 + threadIdx.x;
    if (e >= EE) return;
    int i = eidx[e], j = eidx[EE + e];
    float dx = pos[3*j+0] - pos[3*i+0];
    float dy = pos[3*j+1] - pos[3*i+1];
    float dz = pos[3*j+2] - pos[3*i+2];
    float r = sqrtf(dx*dx + dy*dy + dz*dz + 1e-12f);
    if (!(r >= 0.3f && r < 5.0f)) return;
    int slot = atomicAdd(&cursor[i], 1);
    ei[slot] = i; ej[slot] = j;
    float ir = 1.f / (r + 1e-6f);
    float x = dx*ir, y = dy*ir, z = dz*ir;
    const float s3 = 1.7320508075688772f, s5 = 2.23606797749979f, s15 = 3.872983346207417f;
    float* shp = sh + (size_t)slot * 8;
    shp[0] = s3*y; shp[1] = s3*z; shp[2] = s3*x;
    shp[3] = s15*x*y; shp[4] = s15*y*z; shp[5] = 0.5f*s5*(3.f*z*z - 1.f);
    shp[6] = s15*z*x; shp[7] = 0.5f*s15*(x*x - y*y);
    float fc = 0.5f * (cosf(3.14159265358979323846f * r * 0.2f) + 1.f);
    float pref = 0.6324555320336759f * fc * ir;
    unsigned short* rp = rbfq + (size_t)slot * RR;
    for (int k = 0; k < RR; k++) rp[k] = f2bf(pref * sinf(freq[k] * r * 0.2f));
}

// ---------------------------------------------------------------------------
// S = swish(emb_table[z] @ emb_W + emb_b)
// ---------------------------------------------------------------------------
__global__ __launch_bounds__(128) void embed_kernel(
    const int* __restrict__ z, const float* __restrict__ emb_table,
    const float* __restrict__ emb_W, const float* __restrict__ emb_b,
    float* __restrict__ S)
{
    int n = blockIdx.x;
    int f = threadIdx.x;
    __shared__ float row[FF];
    row[f] = emb_table[(size_t)z[n]*FF + f];
    __syncthreads();
    float acc = emb_b[f];
    for (int k = 0; k < FF; k++) acc += row[k] * emb_W[k*FF + f];
    S[(size_t)n*FF + f] = swishf(acc);
}

// ---------------------------------------------------------------------------
// Node-weight pack (hi/lo split): W1o@0, W1e@16384, W2e@32768, Wup@49152;
// per-layer stride 114688 elems.
// ---------------------------------------------------------------------------
__global__ __launch_bounds__(256) void pack_kernel(
    const float* __restrict__ W1o, const float* __restrict__ W1e,
    const float* __restrict__ W2e, const float* __restrict__ Wup,
    unsigned short* __restrict__ ph, unsigned short* __restrict__ pl)
{
    int t = blockIdx.x * 256 + threadIdx.x;
    if (t >= 3 * 14336) return;
    int b = t / 14336, r = t % 14336;
    const float* src; int nks; size_t dstoff;
    if (r < 6144) {
        int mat = r / 2048, rr = r % 2048;
        src = (mat == 0 ? W1o : mat == 1 ? W1e : W2e) + (size_t)b * 16384;
        nks = 4;
        dstoff = (size_t)b * 114688 + (size_t)mat * 16384 + (size_t)rr * 8;
        r = rr;
    } else {
        int rr = r - 6144;
        src = Wup + (size_t)b * 65536;
        nks = 16;
        dstoff = (size_t)b * 114688 + 49152 + (size_t)rr * 8;
        r = rr;
    }
    int lane = r & 63;
    int fi = r >> 6;
    int ks = fi % nks, ct = fi / nks;
    int col = ct * 16 + (lane & 15);
    int kb = ks * 32 + (lane >> 4) * 8;
    #pragma unroll
    for (int e = 0; e < 8; e++) {
        float v = src[(size_t)(kb + e) * 128 + col];
        unsigned short h = f2bf(v);
        ph[dstoff + e] = h;
        pl[dstoff + e] = f2bf(v - bf2f(h));
    }
}

// ---------------------------------------------------------------------------
// Pack [Wsrc | Wu] (K=128, N=512) into bf16 B-frags.
// ---------------------------------------------------------------------------
__global__ __launch_bounds__(256) void pack_pu_kernel(
    const float* __restrict__ Wsrc, const float* __restrict__ Wu,
    unsigned short* __restrict__ packPU)
{
    int t = blockIdx.x * 256 + threadIdx.x;
    if (t >= 3 * 8192) return;
    int b = t / 8192, r = t % 8192;
    int lane = r & 63, fi = r >> 6;       // fi = ct*4+ks
    int ks = fi & 3, ct = fi >> 2;
    int kb = ks * 32 + (lane >> 4) * 8;
    int colq = lane & 15;
    const float* src; int col, stride;
    if (ct < 8) { src = Wsrc + (size_t)b * 16384; col = ct*16 + colq; stride = 128; }
    else        { src = Wu   + (size_t)b * 49152; col = (ct-8)*16 + colq; stride = 384; }
    size_t dst = (size_t)b * 65536 + (size_t)fi * 512 + (size_t)lane * 8;
    #pragma unroll
    for (int e = 0; e < 8; e++)
        packPU[dst + e] = f2bf(src[(size_t)(kb + e) * stride + col]);
}

// ---------------------------------------------------------------------------
// Pack Wf2 (K=128, N=512) into bf16 B-frags.
// ---------------------------------------------------------------------------
__global__ __launch_bounds__(256) void pack_f2_kernel(
    const float* __restrict__ Wf2, unsigned short* __restrict__ packF2)
{
    int t = blockIdx.x * 256 + threadIdx.x;
    if (t >= 3 * 8192) return;
    int b = t / 8192, r = t % 8192;
    int lane = r & 63, fi = r >> 6;
    int ks = fi & 3, ct = fi >> 2;
    int kb = ks * 32 + (lane >> 4) * 8;
    int col = ct * 16 + (lane & 15);
    const float* src = Wf2 + (size_t)b * 65536;
    size_t dst = (size_t)b * 65536 + (size_t)fi * 512 + (size_t)lane * 8;
    #pragma unroll
    for (int e = 0; e < 8; e++)
        packF2[dst + e] = f2bf(src[(size_t)(kb + e) * 512 + col]);
}

// ---------------------------------------------------------------------------
// Standalone projection (layer 0 only): PU = [swish(S@Wsrc) | S@Wu], MFMA.
// INTERLEAVED output: PU[n*512 + f*4 + c], c in {0:P,1:U1,2:U2,3:U3}.
// ---------------------------------------------------------------------------
__global__ __launch_bounds__(256) void proj_kernel(
    const float* __restrict__ S, const unsigned short* __restrict__ packPU,
    unsigned short* __restrict__ PU)
{
    __shared__ float stage[16][132];
    const int tid = threadIdx.x;
    const int n0 = blockIdx.x * 16;

    for (int idx = tid; idx < 512; idx += 256) {
        int row = idx >> 5, k4 = (idx & 31) << 2;
        *(float4*)&stage[row][k4] = *(const float4*)&S[((size_t)(n0 + row) << 7) + k4];
    }
    __syncthreads();

    const int lane = tid & 63;
    const int wid  = tid >> 6;
    const int row  = lane & 15;
    const int k0   = (lane >> 4) * 8;

    f32x4 acc[8];
    #pragma unroll
    for (int c = 0; c < 8; c++) acc[c] = (f32x4){0.f, 0.f, 0.f, 0.f};

    #pragma unroll
    for (int ks = 0; ks < 4; ks++) {
        const float* sp = &stage[row][ks*32 + k0];
        bf16x8 a;
        #pragma unroll
        for (int e = 0; e < 8; e++) a[e] = (short)f2bf(sp[e]);
        #pragma unroll
        for (int cti = 0; cti < 8; cti++) {
            int ct = wid * 8 + cti;
            bf16x8 b = *(const bf16x8*)(packPU + (((size_t)ct * 4 + ks) * 64 + lane) * 8);
            acc[cti] = __builtin_amdgcn_mfma_f32_16x16x32_bf16(a, b, acc[cti], 0, 0, 0);
        }
    }

    #pragma unroll
    for (int cti = 0; cti < 8; cti++) {
        int ct = wid * 8 + cti;
        int cblk = ct >> 3;
        int fcol = (ct & 7) * 16 + (lane & 15);
        #pragma unroll
        for (int q = 0; q < 4; q++) {
            int n = n0 + (lane >> 4) * 4 + q;
            float v = acc[cti][q];
            if (cblk == 0) v = swishf(v);
            PU[(size_t)n * 512 + fcol * 4 + cblk] = f2bf(v);
        }
    }
}

// ---------------------------------------------------------------------------
// hw_kernel: dense edge GEMM. 32 edges/block.
//   h = swish(rbf@Wf1+bf1) (VALU) -> w = h@Wf2 (MFMA, M=32 x N=512 x K=128)
//   -> wbuf[e][fcol*4+cblk] bf16 interleaved. No formation, no gathers.
// ---------------------------------------------------------------------------
__global__ __launch_bounds__(256) void hw_kernel(
    const int* __restrict__ cstartNN,
    const unsigned short* __restrict__ rbfq,
    const float* __restrict__ Wf1, const float* __restrict__ bf1,
    const unsigned short* __restrict__ packF2,
    unsigned short* __restrict__ wbuf)
{
    const int Ea = *cstartNN;
    const int base = blockIdx.x * 32;
    if (base >= Ea) return;
    const int nval = min(32, Ea - base);
    const int tid = threadIdx.x;
    const int f = tid & 127;
    const int half = tid >> 7;
    const int lane = tid & 63;
    const int wid  = tid >> 6;

    __shared__ float          rbf_s[32][RR];
    __shared__ unsigned short h_s[32][FF];

    for (int t = tid; t < 32*RR; t += 256) {
        int e = t >> 5, k = t & 31;
        rbf_s[e][k] = (e < nval) ? bf2f(rbfq[(size_t)(base + e)*RR + k]) : 0.f;
    }
    __syncthreads();

    // h for 16 edges per (f, half) thread
    {
        float hacc[16];
        float bb = bf1[f];
        #pragma unroll
        for (int k = 0; k < 16; k++) hacc[k] = bb;
        for (int r = 0; r < RR; r++) {
            float wv = Wf1[r*FF + f];
            #pragma unroll
            for (int k = 0; k < 16; k++) hacc[k] += rbf_s[half*16 + k][r] * wv;
        }
        #pragma unroll
        for (int k = 0; k < 16; k++)
            h_s[half*16 + k][f] = f2bf(swishf(hacc[k]));
    }
    __syncthreads();

    // w = h @ Wf2: 2 row-tiles x 8 col-tiles per wave (wave wid owns cblk=wid)
    const int ra = lane & 15, k0 = (lane >> 4) * 8;
    f32x4 acc[2][8];
    #pragma unroll
    for (int rt = 0; rt < 2; rt++)
        #pragma unroll
        for (int c = 0; c < 8; c++) acc[rt][c] = (f32x4){0.f, 0.f, 0.f, 0.f};

    #pragma unroll
    for (int ks = 0; ks < 4; ks++) {
        bf16x8 a0 = *(const bf16x8*)&h_s[ra][ks*32 + k0];
        bf16x8 a1 = *(const bf16x8*)&h_s[16 + ra][ks*32 + k0];
        #pragma unroll
        for (int cti = 0; cti < 8; cti++) {
            int ct = wid * 8 + cti;
            bf16x8 b = *(const bf16x8*)(packF2 + (((size_t)ct * 4 + ks) * 64 + lane) * 8);
            acc[0][cti] = __builtin_amdgcn_mfma_f32_16x16x32_bf16(a0, b, acc[0][cti], 0, 0, 0);
            acc[1][cti] = __builtin_amdgcn_mfma_f32_16x16x32_bf16(a1, b, acc[1][cti], 0, 0, 0);
        }
    }

    #pragma unroll
    for (int rt = 0; rt < 2; rt++) {
        #pragma unroll
        for (int cti = 0; cti < 8; cti++) {
            int fcol = cti * 16 + (lane & 15);
            #pragma unroll
            for (int q = 0; q < 4; q++) {
                int e = base + rt*16 + (lane >> 4) * 4 + q;
                wbuf[(size_t)e * 512 + fcol*4 + wid] = f2bf(acc[rt][cti][q]);
            }
        }
    }
}

// ---------------------------------------------------------------------------
// form_kernel: formation only. 16 i-sorted edges/block, no MFMA, no big LDS.
//  Fully-unrolled break-free prefetch of w + PU into registers; predicated
//  accumulate; hybrid flush (interior: store, boundary: atomicAdd).
// ---------------------------------------------------------------------------
__global__ __launch_bounds__(256) void form_kernel(
    const int* __restrict__ cstart,
    const int* __restrict__ ei, const int* __restrict__ ej,
    const float* __restrict__ sh,
    const unsigned short* __restrict__ wbuf, const unsigned short* __restrict__ PU,
    float* __restrict__ aggS, float* __restrict__ aggT)
{
    const int Ea = cstart[NN];
    const int base = blockIdx.x * MTE;
    if (base >= Ea) return;
    const int nval = min(MTE, Ea - base);
    const int tid = threadIdx.x;
    const int f = tid & 127;
    const int half = tid >> 7;

    __shared__ float sh_s[MTE][8];
    __shared__ int   i_s[MTE], j_s[MTE];

    if (tid < MTE) {
        i_s[tid] = (tid < nval) ? ei[base + tid] : -1;
        j_s[tid] = (tid < nval) ? ej[base + tid] : 0;
    }
    if (tid >= 64 && tid < 64 + MTE*8) {
        int t = tid - 64, e = t >> 3;
        sh_s[e][t & 7] = (e < nval) ? sh[(size_t)(base + e)*8 + (t & 7)] : 0.f;
    }
    __syncthreads();

    // prefetch: constant-indexed, no break -> stays in registers
    uint2 wv[MTE], puv[MTE];
    #pragma unroll
    for (int e = 0; e < MTE; e++) {
        wv[e]  = *(const uint2*)(wbuf + (size_t)(base + e) * 512 + (f << 2));
        puv[e] = *(const uint2*)(PU + ((size_t)j_s[e] << 9) + (f << 2));
    }

    float aS=0.f, a3=0.f, a4=0.f, a5=0.f;                            // half 0
    float a0=0.f,a1=0.f,a2=0.f,a6=0.f,a7=0.f,a8=0.f,a9=0.f,a10=0.f;  // half 1
    int cur = i_s[0];

    auto flush = [&](int node) {
        bool interior = (cstart[node] >= base) && (cstart[node + 1] <= base + nval);
        if (half == 0) {
            size_t sA = ((size_t)node << 7) + f;
            size_t bT = (((size_t)node*11 + 3) << 7) + f;
            if (interior) {
                aggS[sA] = aS;
                aggT[bT] = a3; aggT[bT + 128] = a4; aggT[bT + 256] = a5;
            } else {
                atomicAdd(&aggS[sA], aS);
                atomicAdd(&aggT[bT], a3); atomicAdd(&aggT[bT + 128], a4); atomicAdd(&aggT[bT + 256], a5);
            }
            aS = a3 = a4 = a5 = 0.f;
        } else {
            size_t bT  = (((size_t)node*11) << 7) + f;
            size_t bT2 = (((size_t)node*11 + 6) << 7) + f;
            if (interior) {
                aggT[bT] = a0; aggT[bT + 128] = a1; aggT[bT + 256] = a2;
                aggT[bT2] = a6; aggT[bT2 + 128] = a7; aggT[bT2 + 256] = a8;
                aggT[bT2 + 384] = a9; aggT[bT2 + 512] = a10;
            } else {
                atomicAdd(&aggT[bT], a0); atomicAdd(&aggT[bT + 128], a1); atomicAdd(&aggT[bT + 256], a2);
                atomicAdd(&aggT[bT2], a6); atomicAdd(&aggT[bT2 + 128], a7); atomicAdd(&aggT[bT2 + 256], a8);
                atomicAdd(&aggT[bT2 + 384], a9); atomicAdd(&aggT[bT2 + 512], a10);
            }
            a0=a1=a2=a6=a7=a8=a9=a10=0.f;
        }
    };

    #pragma unroll
    for (int e = 0; e < MTE; e++) {
        bool val = (e < nval);
        float m = val ? 1.f : 0.f;
        int ie = val ? i_s[e] : cur;
        if (ie != cur) { flush(cur); cur = ie; }
        uint2 wv2 = wv[e];
        uint2 pv  = puv[e];
        if (half == 0) {
            float wS = bf2f((unsigned short)(wv2.x & 0xffff));
            float w2 = bf2f((unsigned short)(wv2.y & 0xffff));
            float P  = bf2f((unsigned short)(pv.x  & 0xffff));
            float U2 = bf2f((unsigned short)(pv.y  & 0xffff));
            aS += m * wS * P;
            float v = m * w2 * U2;
            a3 += sh_s[e][0]*v; a4 += sh_s[e][1]*v; a5 += sh_s[e][2]*v;
        } else {
            float w1 = bf2f((unsigned short)(wv2.x >> 16));
            float w3 = bf2f((unsigned short)(wv2.y >> 16));
            float U1 = bf2f((unsigned short)(pv.x  >> 16));
            float U3 = bf2f((unsigned short)(pv.y  >> 16));
            float v1 = m * w1 * U1;
            a0 += sh_s[e][0]*v1; a1 += sh_s[e][1]*v1; a2 += sh_s[e][2]*v1;
            float v3 = m * w3 * U3;
            a6 += sh_s[e][3]*v3; a7 += sh_s[e][4]*v3; a8 += sh_s[e][5]*v3;
            a9 += sh_s[e][6]*v3; a10 += sh_s[e][7]*v3;
        }
    }
    flush(cur);
}

// ---------------------------------------------------------------------------
// T-GEMM via MFMA (bf16 hi/lo split) — R3 version (validated fast).
// ---------------------------------------------------------------------------
template<int GSIZE>
__global__ __launch_bounds__(256) void tgemm_kernel(
    const float* __restrict__ aggT,
    const unsigned short* __restrict__ Wh, const unsigned short* __restrict__ Wl,
    float* __restrict__ T, float* __restrict__ inv,
    int goff, int invoff, int addT)
{
    __shared__ float stage[GSIZE][16][132];
    const int tid = threadIdx.x;
    const int n0 = blockIdx.x * 16;

    const int total = GSIZE * 16 * 32;
    for (int idx = tid; idx < total; idx += 256) {
        int mg  = idx >> 9;
        int rem = idx & 511;
        int row = rem >> 5;
        int k4  = (rem & 31) << 2;
        size_t g = (((size_t)(n0 + row) * 11 + goff + mg) << 7) + k4;
        float4 v = *(const float4*)&aggT[g];
        if (addT) {
            float4 tv = *(const float4*)&T[g];
            v.x += tv.x; v.y += tv.y; v.z += tv.z; v.w += tv.w;
        }
        *(float4*)&stage[mg][row][k4] = v;
    }
    __syncthreads();

    const int lane = tid & 63;
    const int wid  = tid >> 6;
    const int row  = lane & 15;
    const int k0   = (lane >> 4) * 8;

    f32x4 acc[GSIZE][2];
    #pragma unroll
    for (int mg = 0; mg < GSIZE; mg++) {
        acc[mg][0] = (f32x4){0.f, 0.f, 0.f, 0.f};
        acc[mg][1] = (f32x4){0.f, 0.f, 0.f, 0.f};
    }

    #pragma unroll
    for (int ks = 0; ks < 4; ks++) {
        bf16x8 ah[GSIZE], al[GSIZE];
        #pragma unroll
        for (int mg = 0; mg < GSIZE; mg++) {
            const float* sp = &stage[mg][row][ks*32 + k0];
            float v0[4], v1[4];
            *(float4*)v0 = *(const float4*)sp;
            *(float4*)v1 = *(const float4*)(sp + 4);
            #pragma unroll
            for (int e = 0; e < 4; e++) {
                unsigned short h0 = f2bf(v0[e]);
                ah[mg][e]   = (short)h0;
                al[mg][e]   = (short)f2bf(v0[e] - bf2f(h0));
                unsigned short h1 = f2bf(v1[e]);
                ah[mg][4+e] = (short)h1;
                al[mg][4+e] = (short)f2bf(v1[e] - bf2f(h1));
            }
        }
        #pragma unroll
        for (int cti = 0; cti < 2; cti++) {
            const int ct = wid * 2 + cti;
            size_t boff = (((size_t)ct * 4 + ks) * 64 + lane) * 8;
            bf16x8 bh = *(const bf16x8*)(Wh + boff);
            bf16x8 bl = *(const bf16x8*)(Wl + boff);
            #pragma unroll
            for (int mg = 0; mg < GSIZE; mg++) {
                acc[mg][cti] = __builtin_amdgcn_mfma_f32_16x16x32_bf16(ah[mg], bh, acc[mg][cti], 0, 0, 0);
                acc[mg][cti] = __builtin_amdgcn_mfma_f32_16x16x32_bf16(al[mg], bh, acc[mg][cti], 0, 0, 0);
                acc[mg][cti] = __builtin_amdgcn_mfma_f32_16x16x32_bf16(ah[mg], bl, acc[mg][cti], 0, 0, 0);
            }
        }
    }

    #pragma unroll
    for (int cti = 0; cti < 2; cti++) {
        const int ct = wid * 2 + cti;
        const int fc = ct * 16 + (lane & 15);
        #pragma unroll
        for (int q = 0; q < 4; q++) {
            const int n = n0 + (lane >> 4) * 4 + q;
            float iv = 0.f;
            #pragma unroll
            for (int mg = 0; mg < GSIZE; mg++) {
                float o = acc[mg][cti][q];
                T[(((size_t)n * 11 + goff + mg) << 7) + fc] = o;
                iv += o * o;
            }
            inv[(size_t)n * 384 + invoff + fc] = iv;
        }
    }
}

// ---------------------------------------------------------------------------
// S += swish([aggS | inv] @ Wup) + fused next-layer PU projection.
// ---------------------------------------------------------------------------
__global__ __launch_bounds__(256) void sgemm2_kernel(
    const float* __restrict__ aggS, const float* __restrict__ inv,
    const unsigned short* __restrict__ Wh, const unsigned short* __restrict__ Wl,
    const unsigned short* __restrict__ packPUn,
    float* __restrict__ S, unsigned short* __restrict__ PU, int doPU)
{
    __shared__ float stage[16][516];
    __shared__ float snew[16][132];
    const int tid = threadIdx.x;
    const int n0 = blockIdx.x * 16;

    for (int idx = tid; idx < 16 * 128; idx += 256) {
        int row = idx >> 7;
        int k4  = (idx & 127) << 2;
        float4 v;
        if (k4 < 128) v = *(const float4*)&aggS[((size_t)(n0 + row) << 7) + k4];
        else          v = *(const float4*)&inv[(size_t)(n0 + row) * 384 + (k4 - 128)];
        *(float4*)&stage[row][k4] = v;
    }
    __syncthreads();

    const int lane = tid & 63;
    const int wid  = tid >> 6;
    const int row  = lane & 15;
    const int k0   = (lane >> 4) * 8;

    f32x4 acc[2];
    acc[0] = (f32x4){0.f, 0.f, 0.f, 0.f};
    acc[1] = (f32x4){0.f, 0.f, 0.f, 0.f};

    for (int ks = 0; ks < 16; ks++) {
        const float* sp = &stage[row][ks*32 + k0];
        float v0[4], v1[4];
        *(float4*)v0 = *(const float4*)sp;
        *(float4*)v1 = *(const float4*)(sp + 4);
        bf16x8 ah, al;
        #pragma unroll
        for (int e = 0; e < 4; e++) {
            unsigned short h0 = f2bf(v0[e]);
            ah[e]   = (short)h0;
            al[e]   = (short)f2bf(v0[e] - bf2f(h0));
            unsigned short h1 = f2bf(v1[e]);
            ah[4+e] = (short)h1;
            al[4+e] = (short)f2bf(v1[e] - bf2f(h1));
        }
        #pragma unroll
        for (int cti = 0; cti < 2; cti++) {
            const int ct = wid * 2 + cti;
            size_t boff = (((size_t)ct * 16 + ks) * 64 + lane) * 8;
            bf16x8 bh = *(const bf16x8*)(Wh + boff);
            bf16x8 bl = *(const bf16x8*)(Wl + boff);
            acc[cti] = __builtin_amdgcn_mfma_f32_16x16x32_bf16(ah, bh, acc[cti], 0, 0, 0);
            acc[cti] = __builtin_amdgcn_mfma_f32_16x16x32_bf16(al, bh, acc[cti], 0, 0, 0);
            acc[cti] = __builtin_amdgcn_mfma_f32_16x16x32_bf16(ah, bl, acc[cti], 0, 0, 0);
        }
    }

    #pragma unroll
    for (int cti = 0; cti < 2; cti++) {
        const int ct = wid * 2 + cti;
        const int fc = ct * 16 + (lane & 15);
        #pragma unroll
        for (int q = 0; q < 4; q++) {
            const int n = n0 + (lane >> 4) * 4 + q;
            size_t o = ((size_t)n << 7) + fc;
            float sv = S[o] + swishf(acc[cti][q]);
            S[o] = sv;
            snew[(lane >> 4)*4 + q][fc] = sv;
        }
    }

    if (!doPU) return;
    __syncthreads();

    {
        f32x4 pacc[8];
        #pragma unroll
        for (int c = 0; c < 8; c++) pacc[c] = (f32x4){0.f, 0.f, 0.f, 0.f};
        #pragma unroll
        for (int ks = 0; ks < 4; ks++) {
            bf16x8 a;
            #pragma unroll
            for (int e = 0; e < 8; e++)
                a[e] = (short)f2bf(snew[row][ks*32 + k0 + e]);
            #pragma unroll
            for (int cti = 0; cti < 8; cti++) {
                int ct = wid * 8 + cti;
                bf16x8 b = *(const bf16x8*)(packPUn + (((size_t)ct * 4 + ks) * 64 + lane) * 8);
                pacc[cti] = __builtin_amdgcn_mfma_f32_16x16x32_bf16(a, b, pacc[cti], 0, 0, 0);
            }
        }
        #pragma unroll
        for (int cti = 0; cti < 8; cti++) {
            int ct = wid * 8 + cti;
            int cblk = ct >> 3;
            int fcol = (ct & 7) * 16 + (lane & 15);
            #pragma unroll
            for (int q = 0; q < 4; q++) {
                int n = n0 + (lane >> 4) * 4 + q;
                float v = pacc[cti][q];
                if (cblk == 0) v = swishf(v);
                PU[((size_t)n << 9) + fcol*4 + cblk] = f2bf(v);
            }
        }
    }
}

// ---------------------------------------------------------------------------
extern "C" void kernel_launch(void* const* d_in, const int* in_sizes, int n_in,
                              void* d_out, int out_size, void* d_ws, size_t ws_size,
                              hipStream_t stream)
{
    const int*   z         = (const int*)  d_in[0];
    const float* pos       = (const float*)d_in[1];
    const int*   eidx      = (const int*)  d_in[2];
    const float* emb_table = (const float*)d_in[3];
    const float* emb_W     = (const float*)d_in[4];
    const float* emb_b     = (const float*)d_in[5];
    const float* freq      = (const float*)d_in[6];
    const float* Wf1       = (const float*)d_in[7];
    const float* bf1       = (const float*)d_in[8];
    const float* Wf2       = (const float*)d_in[9];
    const float* Wsrc      = (const float*)d_in[10];
    const float* Wu        = (const float*)d_in[11];
    const float* W1o       = (const float*)d_in[12];
    const float* W1e       = (const float*)d_in[13];
    const float* W2e       = (const float*)d_in[14];
    const float* Wup       = (const float*)d_in[15];

    float* S = (float*)d_out;                  // (N,F)
    float* T = S + (size_t)NN*FF;              // (N,11,F)

    char* w0 = (char*)d_ws;
    char* w = w0;
    int*   deg     = (int*)w;                     w += (size_t)NN*4 + 128;
    int*   cursor  = (int*)w;                     w += (size_t)NN*4 + 128;
    int*   cstart  = (int*)w;                     w += (size_t)(NN+1)*4 + 124;
    int*   clearcnt= (int*)w;                     w += 128;
    int*   clearlist=(int*)w;                     w += (size_t)NN*4 + 128;
    int*   ei      = (int*)w;                     w += (size_t)EE*4;
    int*   ej      = (int*)w;                     w += (size_t)EE*4;
    float* sh      = (float*)w;                   w += (size_t)EE*8*4;
    unsigned short* rbfq = (unsigned short*)w;    w += (size_t)EE*RR*2;
    unsigned short* PU   = (unsigned short*)w;    w += (size_t)NN*512*2;
    float* aggS    = (float*)w;                   w += (size_t)NN*FF*4;
    float* aggT    = (float*)w;                   w += (size_t)NN*11*FF*4;
    float* inv     = (float*)w;                   w += (size_t)NN*384*4;
    unsigned short* packH  = (unsigned short*)w;  w += (size_t)344064*2;
    unsigned short* packL  = (unsigned short*)w;  w += (size_t)344064*2;
    unsigned short* packPU = (unsigned short*)w;  w += (size_t)3*65536*2;
    unsigned short* packF2 = (unsigned short*)w;  w += (size_t)3*65536*2;
    unsigned short* wbuf   = (unsigned short*)w;  w += (size_t)WCAP*512*2;   // 128 MB

    if ((size_t)(w - w0) > ws_size) return;   // loud failure instead of OOB

    hipMemsetAsync(deg, 0, (size_t)NN*4, stream);
    hipMemsetAsync(clearcnt, 0, 4, stream);

    geom_deg_kernel<<<(EE + 255)/256, 256, 0, stream>>>(pos, eidx, deg);
    scan_kernel<<<1, 256, 0, stream>>>(deg, cursor, cstart);
    clearlist_kernel<<<(NN + 255)/256, 256, 0, stream>>>(cstart, clearlist, clearcnt);
    geom_scatter_kernel<<<(EE + 255)/256, 256, 0, stream>>>(pos, eidx, freq, cursor, ei, ej, sh, rbfq);
    embed_kernel<<<NN, 128, 0, stream>>>(z, emb_table, emb_W, emb_b, S);
    pack_kernel<<<(3*14336 + 255)/256, 256, 0, stream>>>(W1o, W1e, W2e, Wup, packH, packL);
    pack_pu_kernel<<<(3*8192 + 255)/256, 256, 0, stream>>>(Wsrc, Wu, packPU);
    pack_f2_kernel<<<(3*8192 + 255)/256, 256, 0, stream>>>(Wf2, packF2);

    proj_kernel<<<NN/16, 256, 0, stream>>>(S, packPU, PU);   // layer-0 PU

    for (int b = 0; b < 3; b++) {
        clear_kernel<<<2048, 256, 0, stream>>>(clearlist, clearcnt, aggS, aggT);
        hw_kernel<<<WCAP/32, 256, 0, stream>>>(
            cstart + NN, rbfq,
            Wf1 + (size_t)b*RR*FF, bf1 + (size_t)b*FF,
            packF2 + (size_t)b*65536, wbuf);
        form_kernel<<<WCAP/16, 256, 0, stream>>>(
            cstart, ei, ej, sh, wbuf, PU, aggS, aggT);

        const unsigned short* H = packH + (size_t)b*114688;
        const unsigned short* L = packL + (size_t)b*114688;
        tgemm_kernel<3><<<NN/16, 256, 0, stream>>>(aggT, H +     0, L +     0, T, inv, 0,   0, b > 0);
        tgemm_kernel<3><<<NN/16, 256, 0, stream>>>(aggT, H + 16384, L + 16384, T, inv, 3, 128, b > 0);
        tgemm_kernel<5><<<NN/16, 256, 0, stream>>>(aggT, H + 32768, L + 32768, T, inv, 6, 256, b > 0);
        sgemm2_kernel<<<NN/16, 256, 0, stream>>>(
            aggS, inv, H + 49152, L + 49152,
            packPU + (size_t)(b < 2 ? (b+1)*65536 : 0),
            S, PU, b < 2);
    }
}

// Round 11
// 963.188 us; speedup vs baseline: 1.3169x; 1.2257x over previous
//
#include <hip/hip_runtime.h>
#include <cstdint>
#include <cstddef>

#define NN 20000
#define EE 320000
#define FF 128
#define RR 32
#define MTE 16   // edges per msg block

typedef float  f32x4  __attribute__((ext_vector_type(4)));
typedef short  bf16x8 __attribute__((ext_vector_type(8)));

__device__ __forceinline__ float swishf(float x) {
    return x / (1.f + __expf(-x));
}
__device__ __forceinline__ unsigned short f2bf(float f) {
    unsigned int u = __builtin_bit_cast(unsigned int, f);
    u = (u + 0x7FFFu + ((u >> 16) & 1u)) >> 16;
    return (unsigned short)u;
}
__device__ __forceinline__ float bf2f(unsigned short h) {
    unsigned int u = ((unsigned int)h) << 16;
    return __builtin_bit_cast(float, u);
}

// ---------------------------------------------------------------------------
// Pass 1: active-edge degree histogram over destination i
// ---------------------------------------------------------------------------
__global__ __launch_bounds__(256) void geom_deg_kernel(
    const float* __restrict__ pos, const int* __restrict__ eidx,
    int* __restrict__ deg)
{
    int e = blockIdx.x * 256 + threadIdx.x;
    if (e >= EE) return;
    int i = eidx[e], j = eidx[EE + e];
    float dx = pos[3*j+0] - pos[3*i+0];
    float dy = pos[3*j+1] - pos[3*i+1];
    float dz = pos[3*j+2] - pos[3*i+2];
    float r = sqrtf(dx*dx + dy*dy + dz*dz + 1e-12f);
    if (r >= 0.3f && r < 5.0f) atomicAdd(&deg[i], 1);
}

// ---------------------------------------------------------------------------
// Exclusive scan: cursor (consumed by scatter) + cstart (preserved; [NN]=total)
// ---------------------------------------------------------------------------
__global__ __launch_bounds__(256) void scan_kernel(
    const int* __restrict__ deg, int* __restrict__ cursor, int* __restrict__ cstart)
{
    __shared__ int part[256];
    const int t = threadIdx.x;
    const int lo = t * 79;
    const int hi = min(lo + 79, NN);
    int s = 0;
    for (int k = lo; k < hi; k++) s += deg[k];
    part[t] = s;
    __syncthreads();
    for (int off = 1; off < 256; off <<= 1) {
        int v = (t >= off) ? part[t - off] : 0;
        __syncthreads();
        part[t] += v;
        __syncthreads();
    }
    int run = (t == 0) ? 0 : part[t - 1];
    for (int k = lo; k < hi; k++) { cursor[k] = run; cstart[k] = run; run += deg[k]; }
    if (t == 255) cstart[NN] = part[255];
}

// ---------------------------------------------------------------------------
// Nodes needing zero-init before msg: zero-degree OR tile-boundary crossers.
// ---------------------------------------------------------------------------
__global__ __launch_bounds__(256) void clearlist_kernel(
    const int* __restrict__ cstart, int* __restrict__ list, int* __restrict__ cnt)
{
    int n = blockIdx.x * 256 + threadIdx.x;
    if (n >= NN) return;
    int s = cstart[n], t = cstart[n + 1];
    bool need = (s == t) || ((s >> 4) != ((t - 1) >> 4));
    if (need) list[atomicAdd(cnt, 1)] = n;
}

// ---------------------------------------------------------------------------
// Zero the agg rows of listed nodes (grid-stride).
// ---------------------------------------------------------------------------
__global__ __launch_bounds__(256) void clear_kernel(
    const int* __restrict__ list, const int* __restrict__ cnt,
    float* __restrict__ aggS, float* __restrict__ aggT)
{
    const int total = (*cnt) * 384;    // 12 rows * 32 float4 per node
    const f32x4 z = (f32x4){0.f, 0.f, 0.f, 0.f};
    for (int idx = blockIdx.x * 256 + threadIdx.x; idx < total; idx += gridDim.x * 256) {
        int ni = idx / 384, rem = idx - ni * 384;
        int n = list[ni];
        if (rem < 32) *(f32x4*)&aggS[((size_t)n << 7) + rem * 4] = z;
        else {
            int r = rem - 32;
            *(f32x4*)&aggT[(((size_t)n * 11 + (r >> 5)) << 7) + (r & 31) * 4] = z;
        }
    }
}

// ---------------------------------------------------------------------------
// Pass 2: recompute geometry, scatter active edges into i-sorted slots.
// ---------------------------------------------------------------------------
__global__ __launch_bounds__(256) void geom_scatter_kernel(
    const float* __restrict__ pos, const int* __restrict__ eidx,
    const float* __restrict__ freq, int* __restrict__ cursor,
    int* __restrict__ ei, int* __restrict__ ej,
    float* __restrict__ sh, unsigned short* __restrict__ rbfq)
{
    int e = blockIdx.x * 256 + threadIdx.x;
    if (e >= EE) return;
    int i = eidx[e], j = eidx[EE + e];
    float dx = pos[3*j+0] - pos[3*i+0];
    float dy = pos[3*j+1] - pos[3*i+1];
    float dz = pos[3*j+2] - pos[3*i+2];
    float r = sqrtf(dx*dx + dy*dy + dz*dz + 1e-12f);
    if (!(r >= 0.3f && r < 5.0f)) return;
    int slot = atomicAdd(&cursor[i], 1);
    ei[slot] = i; ej[slot] = j;
    float ir = 1.f / (r + 1e-6f);
    float x = dx*ir, y = dy*ir, z = dz*ir;
    const float s3 = 1.7320508075688772f, s5 = 2.23606797749979f, s15 = 3.872983346207417f;
    float* shp = sh + (size_t)slot * 8;
    shp[0] = s3*y; shp[1] = s3*z; shp[2] = s3*x;
    shp[3] = s15*x*y; shp[4] = s15*y*z; shp[5] = 0.5f*s5*(3.f*z*z - 1.f);
    shp[6] = s15*z*x; shp[7] = 0.5f*s15*(x*x - y*y);
    float fc = 0.5f * (cosf(3.14159265358979323846f * r * 0.2f) + 1.f);
    float pref = 0.6324555320336759f * fc * ir;
    unsigned short* rp = rbfq + (size_t)slot * RR;
    for (int k = 0; k < RR; k++) rp[k] = f2bf(pref * sinf(freq[k] * r * 0.2f));
}

// ---------------------------------------------------------------------------
// S = swish(emb_table[z] @ emb_W + emb_b)
// ---------------------------------------------------------------------------
__global__ __launch_bounds__(128) void embed_kernel(
    const int* __restrict__ z, const float* __restrict__ emb_table,
    const float* __restrict__ emb_W, const float* __restrict__ emb_b,
    float* __restrict__ S)
{
    int n = blockIdx.x;
    int f = threadIdx.x;
    __shared__ float row[FF];
    row[f] = emb_table[(size_t)z[n]*FF + f];
    __syncthreads();
    float acc = emb_b[f];
    for (int k = 0; k < FF; k++) acc += row[k] * emb_W[k*FF + f];
    S[(size_t)n*FF + f] = swishf(acc);
}

// ---------------------------------------------------------------------------
// Node-weight pack (hi/lo split): W1o@0, W1e@16384, W2e@32768, Wup@49152;
// per-layer stride 114688 elems.
// ---------------------------------------------------------------------------
__global__ __launch_bounds__(256) void pack_kernel(
    const float* __restrict__ W1o, const float* __restrict__ W1e,
    const float* __restrict__ W2e, const float* __restrict__ Wup,
    unsigned short* __restrict__ ph, unsigned short* __restrict__ pl)
{
    int t = blockIdx.x * 256 + threadIdx.x;
    if (t >= 3 * 14336) return;
    int b = t / 14336, r = t % 14336;
    const float* src; int nks; size_t dstoff;
    if (r < 6144) {
        int mat = r / 2048, rr = r % 2048;
        src = (mat == 0 ? W1o : mat == 1 ? W1e : W2e) + (size_t)b * 16384;
        nks = 4;
        dstoff = (size_t)b * 114688 + (size_t)mat * 16384 + (size_t)rr * 8;
        r = rr;
    } else {
        int rr = r - 6144;
        src = Wup + (size_t)b * 65536;
        nks = 16;
        dstoff = (size_t)b * 114688 + 49152 + (size_t)rr * 8;
        r = rr;
    }
    int lane = r & 63;
    int fi = r >> 6;
    int ks = fi % nks, ct = fi / nks;
    int col = ct * 16 + (lane & 15);
    int kb = ks * 32 + (lane >> 4) * 8;
    #pragma unroll
    for (int e = 0; e < 8; e++) {
        float v = src[(size_t)(kb + e) * 128 + col];
        unsigned short h = f2bf(v);
        ph[dstoff + e] = h;
        pl[dstoff + e] = f2bf(v - bf2f(h));
    }
}

// ---------------------------------------------------------------------------
// Pack [Wsrc | Wu] (K=128, N=512) into bf16 B-frags.
// ---------------------------------------------------------------------------
__global__ __launch_bounds__(256) void pack_pu_kernel(
    const float* __restrict__ Wsrc, const float* __restrict__ Wu,
    unsigned short* __restrict__ packPU)
{
    int t = blockIdx.x * 256 + threadIdx.x;
    if (t >= 3 * 8192) return;
    int b = t / 8192, r = t % 8192;
    int lane = r & 63, fi = r >> 6;       // fi = ct*4+ks
    int ks = fi & 3, ct = fi >> 2;
    int kb = ks * 32 + (lane >> 4) * 8;
    int colq = lane & 15;
    const float* src; int col, stride;
    if (ct < 8) { src = Wsrc + (size_t)b * 16384; col = ct*16 + colq; stride = 128; }
    else        { src = Wu   + (size_t)b * 49152; col = (ct-8)*16 + colq; stride = 384; }
    size_t dst = (size_t)b * 65536 + (size_t)fi * 512 + (size_t)lane * 8;
    #pragma unroll
    for (int e = 0; e < 8; e++)
        packPU[dst + e] = f2bf(src[(size_t)(kb + e) * stride + col]);
}

// ---------------------------------------------------------------------------
// Pack Wf2 (K=128, N=512) into bf16 B-frags.
// ---------------------------------------------------------------------------
__global__ __launch_bounds__(256) void pack_f2_kernel(
    const float* __restrict__ Wf2, unsigned short* __restrict__ packF2)
{
    int t = blockIdx.x * 256 + threadIdx.x;
    if (t >= 3 * 8192) return;
    int b = t / 8192, r = t % 8192;
    int lane = r & 63, fi = r >> 6;
    int ks = fi & 3, ct = fi >> 2;
    int kb = ks * 32 + (lane >> 4) * 8;
    int col = ct * 16 + (lane & 15);
    const float* src = Wf2 + (size_t)b * 65536;
    size_t dst = (size_t)b * 65536 + (size_t)fi * 512 + (size_t)lane * 8;
    #pragma unroll
    for (int e = 0; e < 8; e++)
        packF2[dst + e] = f2bf(src[(size_t)(kb + e) * 512 + col]);
}

// ---------------------------------------------------------------------------
// Standalone projection (layer 0 only): PU = [swish(S@Wsrc) | S@Wu], MFMA.
// INTERLEAVED output: PU[n*512 + f*4 + c], c in {0:P,1:U1,2:U2,3:U3}.
// ---------------------------------------------------------------------------
__global__ __launch_bounds__(256) void proj_kernel(
    const float* __restrict__ S, const unsigned short* __restrict__ packPU,
    unsigned short* __restrict__ PU)
{
    __shared__ float stage[16][132];
    const int tid = threadIdx.x;
    const int n0 = blockIdx.x * 16;

    for (int idx = tid; idx < 512; idx += 256) {
        int row = idx >> 5, k4 = (idx & 31) << 2;
        *(float4*)&stage[row][k4] = *(const float4*)&S[((size_t)(n0 + row) << 7) + k4];
    }
    __syncthreads();

    const int lane = tid & 63;
    const int wid  = tid >> 6;
    const int row  = lane & 15;
    const int k0   = (lane >> 4) * 8;

    f32x4 acc[8];
    #pragma unroll
    for (int c = 0; c < 8; c++) acc[c] = (f32x4){0.f, 0.f, 0.f, 0.f};

    #pragma unroll
    for (int ks = 0; ks < 4; ks++) {
        const float* sp = &stage[row][ks*32 + k0];
        bf16x8 a;
        #pragma unroll
        for (int e = 0; e < 8; e++) a[e] = (short)f2bf(sp[e]);
        #pragma unroll
        for (int cti = 0; cti < 8; cti++) {
            int ct = wid * 8 + cti;
            bf16x8 b = *(const bf16x8*)(packPU + (((size_t)ct * 4 + ks) * 64 + lane) * 8);
            acc[cti] = __builtin_amdgcn_mfma_f32_16x16x32_bf16(a, b, acc[cti], 0, 0, 0);
        }
    }

    #pragma unroll
    for (int cti = 0; cti < 8; cti++) {
        int ct = wid * 8 + cti;
        int cblk = ct >> 3;
        int fcol = (ct & 7) * 16 + (lane & 15);
        #pragma unroll
        for (int q = 0; q < 4; q++) {
            int n = n0 + (lane >> 4) * 4 + q;
            float v = acc[cti][q];
            if (cblk == 0) v = swishf(v);
            PU[(size_t)n * 512 + fcol * 4 + cblk] = f2bf(v);
        }
    }
}

// ---------------------------------------------------------------------------
// Message kernel (fused, R8 base + R10's proven break-free prefetch):
//  h (VALU) -> w (MFMA, channel-interleaved LDS) -> break-free register
//  prefetch of all 16 PU gathers -> break-free MASKED formation; flush at
//  i-transitions (interior: plain store, boundary: atomicAdd).
// ---------------------------------------------------------------------------
__global__ __launch_bounds__(256) void msg_kernel(
    const int* __restrict__ cstart,
    const int* __restrict__ ei, const int* __restrict__ ej,
    const float* __restrict__ sh, const unsigned short* __restrict__ rbfq,
    const float* __restrict__ Wf1, const float* __restrict__ bf1,
    const unsigned short* __restrict__ packF2, const unsigned short* __restrict__ PU,
    float* __restrict__ aggS, float* __restrict__ aggT)
{
    const int Ea = cstart[NN];
    const int base = blockIdx.x * MTE;
    if (base >= Ea) return;
    const int nval = min(MTE, Ea - base);
    const int tid = threadIdx.x;
    const int f = tid & 127;
    const int half = tid >> 7;
    const int lane = tid & 63;
    const int wid  = tid >> 6;

    __shared__ float          rbf_s[MTE][RR];
    __shared__ unsigned short h_s[MTE][FF];
    __shared__ unsigned short w_s[MTE][520];   // interleaved [fcol*4+cblk]
    __shared__ float          sh_s[MTE][8];
    __shared__ int            i_s[MTE], j_s[MTE];

    if (tid < MTE) {
        i_s[tid] = (tid < nval) ? ei[base + tid] : -1;
        j_s[tid] = (tid < nval) ? ej[base + tid] : 0;
    }
    if (tid >= 64 && tid < 64 + MTE*8) {
        int t = tid - 64, e = t >> 3;
        sh_s[e][t & 7] = (e < nval) ? sh[(size_t)(base + e)*8 + (t & 7)] : 0.f;
    }
    for (int t = tid; t < MTE*RR; t += 256) {
        int e = t >> 5, k = t & 31;
        rbf_s[e][k] = (e < nval) ? bf2f(rbfq[(size_t)(base + e)*RR + k]) : 0.f;
    }
    __syncthreads();

    // h = swish(rbf @ Wf1 + bf1): thread (f,half) does edges half*8..+8
    {
        float hacc[8];
        float bb = bf1[f];
        #pragma unroll
        for (int k = 0; k < 8; k++) hacc[k] = bb;
        for (int r = 0; r < RR; r++) {
            float wv = Wf1[r*FF + f];
            #pragma unroll
            for (int k = 0; k < 8; k++) hacc[k] += rbf_s[half*8 + k][r] * wv;
        }
        #pragma unroll
        for (int k = 0; k < 8; k++)
            h_s[half*8 + k][f] = f2bf(swishf(hacc[k]));
    }
    __syncthreads();

    // w = h @ Wf2 (MFMA); interleaved store
    {
        const int ra = lane & 15, k0 = (lane >> 4) * 8;
        f32x4 wacc[8];
        #pragma unroll
        for (int c = 0; c < 8; c++) wacc[c] = (f32x4){0.f, 0.f, 0.f, 0.f};
        #pragma unroll
        for (int ks = 0; ks < 4; ks++) {
            bf16x8 a = *(const bf16x8*)&h_s[ra][ks*32 + k0];
            #pragma unroll
            for (int cti = 0; cti < 8; cti++) {
                int ct = wid * 8 + cti;
                bf16x8 b = *(const bf16x8*)(packF2 + (((size_t)ct * 4 + ks) * 64 + lane) * 8);
                wacc[cti] = __builtin_amdgcn_mfma_f32_16x16x32_bf16(a, b, wacc[cti], 0, 0, 0);
            }
        }
        #pragma unroll
        for (int cti = 0; cti < 8; cti++) {
            int ct = wid * 8 + cti;
            int cblk = ct >> 3;
            int fcol = (ct & 7) * 16 + (lane & 15);
            #pragma unroll
            for (int q = 0; q < 4; q++)
                w_s[(lane >> 4)*4 + q][fcol*4 + cblk] = f2bf(wacc[cti][q]);
        }
    }
    __syncthreads();

    // break-free prefetch: all 16 PU gathers into registers (R10 form idiom)
    uint2 puv[MTE];
    #pragma unroll
    for (int e = 0; e < MTE; e++)
        puv[e] = *(const uint2*)(PU + ((size_t)j_s[e] << 9) + (f << 2));

    // break-free masked formation; flush at i-transitions (hybrid)
    float aS=0.f, a3=0.f, a4=0.f, a5=0.f;                            // half 0
    float a0=0.f,a1=0.f,a2=0.f,a6=0.f,a7=0.f,a8=0.f,a9=0.f,a10=0.f;  // half 1
    int cur = i_s[0];

    auto flush = [&](int node) {
        bool interior = (cstart[node] >= base) && (cstart[node + 1] <= base + nval);
        if (half == 0) {
            size_t sA = ((size_t)node << 7) + f;
            size_t bT = (((size_t)node*11 + 3) << 7) + f;
            if (interior) {
                aggS[sA] = aS;
                aggT[bT] = a3; aggT[bT + 128] = a4; aggT[bT + 256] = a5;
            } else {
                atomicAdd(&aggS[sA], aS);
                atomicAdd(&aggT[bT], a3); atomicAdd(&aggT[bT + 128], a4); atomicAdd(&aggT[bT + 256], a5);
            }
            aS = a3 = a4 = a5 = 0.f;
        } else {
            size_t bT  = (((size_t)node*11) << 7) + f;
            size_t bT2 = (((size_t)node*11 + 6) << 7) + f;
            if (interior) {
                aggT[bT] = a0; aggT[bT + 128] = a1; aggT[bT + 256] = a2;
                aggT[bT2] = a6; aggT[bT2 + 128] = a7; aggT[bT2 + 256] = a8;
                aggT[bT2 + 384] = a9; aggT[bT2 + 512] = a10;
            } else {
                atomicAdd(&aggT[bT], a0); atomicAdd(&aggT[bT + 128], a1); atomicAdd(&aggT[bT + 256], a2);
                atomicAdd(&aggT[bT2], a6); atomicAdd(&aggT[bT2 + 128], a7); atomicAdd(&aggT[bT2 + 256], a8);
                atomicAdd(&aggT[bT2 + 384], a9); atomicAdd(&aggT[bT2 + 512], a10);
            }
            a0=a1=a2=a6=a7=a8=a9=a10=0.f;
        }
    };

    #pragma unroll
    for (int e = 0; e < MTE; e++) {
        bool val = (e < nval);
        float m = val ? 1.f : 0.f;
        int ie = val ? i_s[e] : cur;
        if (ie != cur) { flush(cur); cur = ie; }
        uint2 wv2 = *(const uint2*)&w_s[e][f*4];
        uint2 pv  = puv[e];
        if (half == 0) {
            float wS = bf2f((unsigned short)(wv2.x & 0xffff));
            float w2 = bf2f((unsigned short)(wv2.y & 0xffff));
            float P  = bf2f((unsigned short)(pv.x  & 0xffff));
            float U2 = bf2f((unsigned short)(pv.y  & 0xffff));
            aS += m * wS * P;
            float v = m * w2 * U2;
            a3 += sh_s[e][0]*v; a4 += sh_s[e][1]*v; a5 += sh_s[e][2]*v;
        } else {
            float w1 = bf2f((unsigned short)(wv2.x >> 16));
            float w3 = bf2f((unsigned short)(wv2.y >> 16));
            float U1 = bf2f((unsigned short)(pv.x  >> 16));
            float U3 = bf2f((unsigned short)(pv.y  >> 16));
            float v1 = m * w1 * U1;
            a0 += sh_s[e][0]*v1; a1 += sh_s[e][1]*v1; a2 += sh_s[e][2]*v1;
            float v3 = m * w3 * U3;
            a6 += sh_s[e][3]*v3; a7 += sh_s[e][4]*v3; a8 += sh_s[e][5]*v3;
            a9 += sh_s[e][6]*v3; a10 += sh_s[e][7]*v3;
        }
    }
    flush(cur);
}

// ---------------------------------------------------------------------------
// T-GEMM via MFMA (bf16 hi/lo split) — R3 version (validated fast).
// ---------------------------------------------------------------------------
template<int GSIZE>
__global__ __launch_bounds__(256) void tgemm_kernel(
    const float* __restrict__ aggT,
    const unsigned short* __restrict__ Wh, const unsigned short* __restrict__ Wl,
    float* __restrict__ T, float* __restrict__ inv,
    int goff, int invoff, int addT)
{
    __shared__ float stage[GSIZE][16][132];
    const int tid = threadIdx.x;
    const int n0 = blockIdx.x * 16;

    const int total = GSIZE * 16 * 32;
    for (int idx = tid; idx < total; idx += 256) {
        int mg  = idx >> 9;
        int rem = idx & 511;
        int row = rem >> 5;
        int k4  = (rem & 31) << 2;
        size_t g = (((size_t)(n0 + row) * 11 + goff + mg) << 7) + k4;
        float4 v = *(const float4*)&aggT[g];
        if (addT) {
            float4 tv = *(const float4*)&T[g];
            v.x += tv.x; v.y += tv.y; v.z += tv.z; v.w += tv.w;
        }
        *(float4*)&stage[mg][row][k4] = v;
    }
    __syncthreads();

    const int lane = tid & 63;
    const int wid  = tid >> 6;
    const int row  = lane & 15;
    const int k0   = (lane >> 4) * 8;

    f32x4 acc[GSIZE][2];
    #pragma unroll
    for (int mg = 0; mg < GSIZE; mg++) {
        acc[mg][0] = (f32x4){0.f, 0.f, 0.f, 0.f};
        acc[mg][1] = (f32x4){0.f, 0.f, 0.f, 0.f};
    }

    #pragma unroll
    for (int ks = 0; ks < 4; ks++) {
        bf16x8 ah[GSIZE], al[GSIZE];
        #pragma unroll
        for (int mg = 0; mg < GSIZE; mg++) {
            const float* sp = &stage[mg][row][ks*32 + k0];
            float v0[4], v1[4];
            *(float4*)v0 = *(const float4*)sp;
            *(float4*)v1 = *(const float4*)(sp + 4);
            #pragma unroll
            for (int e = 0; e < 4; e++) {
                unsigned short h0 = f2bf(v0[e]);
                ah[mg][e]   = (short)h0;
                al[mg][e]   = (short)f2bf(v0[e] - bf2f(h0));
                unsigned short h1 = f2bf(v1[e]);
                ah[mg][4+e] = (short)h1;
                al[mg][4+e] = (short)f2bf(v1[e] - bf2f(h1));
            }
        }
        #pragma unroll
        for (int cti = 0; cti < 2; cti++) {
            const int ct = wid * 2 + cti;
            size_t boff = (((size_t)ct * 4 + ks) * 64 + lane) * 8;
            bf16x8 bh = *(const bf16x8*)(Wh + boff);
            bf16x8 bl = *(const bf16x8*)(Wl + boff);
            #pragma unroll
            for (int mg = 0; mg < GSIZE; mg++) {
                acc[mg][cti] = __builtin_amdgcn_mfma_f32_16x16x32_bf16(ah[mg], bh, acc[mg][cti], 0, 0, 0);
                acc[mg][cti] = __builtin_amdgcn_mfma_f32_16x16x32_bf16(al[mg], bh, acc[mg][cti], 0, 0, 0);
                acc[mg][cti] = __builtin_amdgcn_mfma_f32_16x16x32_bf16(ah[mg], bl, acc[mg][cti], 0, 0, 0);
            }
        }
    }

    #pragma unroll
    for (int cti = 0; cti < 2; cti++) {
        const int ct = wid * 2 + cti;
        const int fc = ct * 16 + (lane & 15);
        #pragma unroll
        for (int q = 0; q < 4; q++) {
            const int n = n0 + (lane >> 4) * 4 + q;
            float iv = 0.f;
            #pragma unroll
            for (int mg = 0; mg < GSIZE; mg++) {
                float o = acc[mg][cti][q];
                T[(((size_t)n * 11 + goff + mg) << 7) + fc] = o;
                iv += o * o;
            }
            inv[(size_t)n * 384 + invoff + fc] = iv;
        }
    }
}

// ---------------------------------------------------------------------------
// S += swish([aggS | inv] @ Wup) + fused next-layer PU projection.
// ---------------------------------------------------------------------------
__global__ __launch_bounds__(256) void sgemm2_kernel(
    const float* __restrict__ aggS, const float* __restrict__ inv,
    const unsigned short* __restrict__ Wh, const unsigned short* __restrict__ Wl,
    const unsigned short* __restrict__ packPUn,
    float* __restrict__ S, unsigned short* __restrict__ PU, int doPU)
{
    __shared__ float stage[16][516];
    __shared__ float snew[16][132];
    const int tid = threadIdx.x;
    const int n0 = blockIdx.x * 16;

    for (int idx = tid; idx < 16 * 128; idx += 256) {
        int row = idx >> 7;
        int k4  = (idx & 127) << 2;
        float4 v;
        if (k4 < 128) v = *(const float4*)&aggS[((size_t)(n0 + row) << 7) + k4];
        else          v = *(const float4*)&inv[(size_t)(n0 + row) * 384 + (k4 - 128)];
        *(float4*)&stage[row][k4] = v;
    }
    __syncthreads();

    const int lane = tid & 63;
    const int wid  = tid >> 6;
    const int row  = lane & 15;
    const int k0   = (lane >> 4) * 8;

    f32x4 acc[2];
    acc[0] = (f32x4){0.f, 0.f, 0.f, 0.f};
    acc[1] = (f32x4){0.f, 0.f, 0.f, 0.f};

    for (int ks = 0; ks < 16; ks++) {
        const float* sp = &stage[row][ks*32 + k0];
        float v0[4], v1[4];
        *(float4*)v0 = *(const float4*)sp;
        *(float4*)v1 = *(const float4*)(sp + 4);
        bf16x8 ah, al;
        #pragma unroll
        for (int e = 0; e < 4; e++) {
            unsigned short h0 = f2bf(v0[e]);
            ah[e]   = (short)h0;
            al[e]   = (short)f2bf(v0[e] - bf2f(h0));
            unsigned short h1 = f2bf(v1[e]);
            ah[4+e] = (short)h1;
            al[4+e] = (short)f2bf(v1[e] - bf2f(h1));
        }
        #pragma unroll
        for (int cti = 0; cti < 2; cti++) {
            const int ct = wid * 2 + cti;
            size_t boff = (((size_t)ct * 16 + ks) * 64 + lane) * 8;
            bf16x8 bh = *(const bf16x8*)(Wh + boff);
            bf16x8 bl = *(const bf16x8*)(Wl + boff);
            acc[cti] = __builtin_amdgcn_mfma_f32_16x16x32_bf16(ah, bh, acc[cti], 0, 0, 0);
            acc[cti] = __builtin_amdgcn_mfma_f32_16x16x32_bf16(al, bh, acc[cti], 0, 0, 0);
            acc[cti] = __builtin_amdgcn_mfma_f32_16x16x32_bf16(ah, bl, acc[cti], 0, 0, 0);
        }
    }

    #pragma unroll
    for (int cti = 0; cti < 2; cti++) {
        const int ct = wid * 2 + cti;
        const int fc = ct * 16 + (lane & 15);
        #pragma unroll
        for (int q = 0; q < 4; q++) {
            const int n = n0 + (lane >> 4) * 4 + q;
            size_t o = ((size_t)n << 7) + fc;
            float sv = S[o] + swishf(acc[cti][q]);
            S[o] = sv;
            snew[(lane >> 4)*4 + q][fc] = sv;
        }
    }

    if (!doPU) return;
    __syncthreads();

    {
        f32x4 pacc[8];
        #pragma unroll
        for (int c = 0; c < 8; c++) pacc[c] = (f32x4){0.f, 0.f, 0.f, 0.f};
        #pragma unroll
        for (int ks = 0; ks < 4; ks++) {
            bf16x8 a;
            #pragma unroll
            for (int e = 0; e < 8; e++)
                a[e] = (short)f2bf(snew[row][ks*32 + k0 + e]);
            #pragma unroll
            for (int cti = 0; cti < 8; cti++) {
                int ct = wid * 8 + cti;
                bf16x8 b = *(const bf16x8*)(packPUn + (((size_t)ct * 4 + ks) * 64 + lane) * 8);
                pacc[cti] = __builtin_amdgcn_mfma_f32_16x16x32_bf16(a, b, pacc[cti], 0, 0, 0);
            }
        }
        #pragma unroll
        for (int cti = 0; cti < 8; cti++) {
            int ct = wid * 8 + cti;
            int cblk = ct >> 3;
            int fcol = (ct & 7) * 16 + (lane & 15);
            #pragma unroll
            for (int q = 0; q < 4; q++) {
                int n = n0 + (lane >> 4) * 4 + q;
                float v = pacc[cti][q];
                if (cblk == 0) v = swishf(v);
                PU[((size_t)n << 9) + fcol*4 + cblk] = f2bf(v);
            }
        }
    }
}

// ---------------------------------------------------------------------------
extern "C" void kernel_launch(void* const* d_in, const int* in_sizes, int n_in,
                              void* d_out, int out_size, void* d_ws, size_t ws_size,
                              hipStream_t stream)
{
    const int*   z         = (const int*)  d_in[0];
    const float* pos       = (const float*)d_in[1];
    const int*   eidx      = (const int*)  d_in[2];
    const float* emb_table = (const float*)d_in[3];
    const float* emb_W     = (const float*)d_in[4];
    const float* emb_b     = (const float*)d_in[5];
    const float* freq      = (const float*)d_in[6];
    const float* Wf1       = (const float*)d_in[7];
    const float* bf1       = (const float*)d_in[8];
    const float* Wf2       = (const float*)d_in[9];
    const float* Wsrc      = (const float*)d_in[10];
    const float* Wu        = (const float*)d_in[11];
    const float* W1o       = (const float*)d_in[12];
    const float* W1e       = (const float*)d_in[13];
    const float* W2e       = (const float*)d_in[14];
    const float* Wup       = (const float*)d_in[15];

    float* S = (float*)d_out;                  // (N,F)
    float* T = S + (size_t)NN*FF;              // (N,11,F)

    char* w = (char*)d_ws;
    int*   deg     = (int*)w;                     w += (size_t)NN*4 + 128;
    int*   cursor  = (int*)w;                     w += (size_t)NN*4 + 128;
    int*   cstart  = (int*)w;                     w += (size_t)(NN+1)*4 + 124;
    int*   clearcnt= (int*)w;                     w += 128;
    int*   clearlist=(int*)w;                     w += (size_t)NN*4 + 128;
    int*   ei      = (int*)w;                     w += (size_t)EE*4;
    int*   ej      = (int*)w;                     w += (size_t)EE*4;
    float* sh      = (float*)w;                   w += (size_t)EE*8*4;
    unsigned short* rbfq = (unsigned short*)w;    w += (size_t)EE*RR*2;
    unsigned short* PU   = (unsigned short*)w;    w += (size_t)NN*512*2;
    float* aggS    = (float*)w;                   w += (size_t)NN*FF*4;
    float* aggT    = (float*)w;                   w += (size_t)NN*11*FF*4;
    float* inv     = (float*)w;                   w += (size_t)NN*384*4;
    unsigned short* packH  = (unsigned short*)w;  w += (size_t)344064*2;
    unsigned short* packL  = (unsigned short*)w;  w += (size_t)344064*2;
    unsigned short* packPU = (unsigned short*)w;  w += (size_t)3*65536*2;
    unsigned short* packF2 = (unsigned short*)w;  w += (size_t)3*65536*2;

    hipMemsetAsync(deg, 0, (size_t)NN*4, stream);
    hipMemsetAsync(clearcnt, 0, 4, stream);

    geom_deg_kernel<<<(EE + 255)/256, 256, 0, stream>>>(pos, eidx, deg);
    scan_kernel<<<1, 256, 0, stream>>>(deg, cursor, cstart);
    clearlist_kernel<<<(NN + 255)/256, 256, 0, stream>>>(cstart, clearlist, clearcnt);
    geom_scatter_kernel<<<(EE + 255)/256, 256, 0, stream>>>(pos, eidx, freq, cursor, ei, ej, sh, rbfq);
    embed_kernel<<<NN, 128, 0, stream>>>(z, emb_table, emb_W, emb_b, S);
    pack_kernel<<<(3*14336 + 255)/256, 256, 0, stream>>>(W1o, W1e, W2e, Wup, packH, packL);
    pack_pu_kernel<<<(3*8192 + 255)/256, 256, 0, stream>>>(Wsrc, Wu, packPU);
    pack_f2_kernel<<<(3*8192 + 255)/256, 256, 0, stream>>>(Wf2, packF2);

    proj_kernel<<<NN/16, 256, 0, stream>>>(S, packPU, PU);   // layer-0 PU

    for (int b = 0; b < 3; b++) {
        clear_kernel<<<2048, 256, 0, stream>>>(clearlist, clearcnt, aggS, aggT);
        msg_kernel<<<(EE + MTE - 1)/MTE, 256, 0, stream>>>(
            cstart, ei, ej, sh, rbfq,
            Wf1 + (size_t)b*RR*FF, bf1 + (size_t)b*FF,
            packF2 + (size_t)b*65536, PU, aggS, aggT);

        const unsigned short* H = packH + (size_t)b*114688;
        const unsigned short* L = packL + (size_t)b*114688;
        tgemm_kernel<3><<<NN/16, 256, 0, stream>>>(aggT, H +     0, L +     0, T, inv, 0,   0, b > 0);
        tgemm_kernel<3><<<NN/16, 256, 0, stream>>>(aggT, H + 16384, L + 16384, T, inv, 3, 128, b > 0);
        tgemm_kernel<5><<<NN/16, 256, 0, stream>>>(aggT, H + 32768, L + 32768, T, inv, 6, 256, b > 0);
        sgemm2_kernel<<<NN/16, 256, 0, stream>>>(
            aggS, inv, H + 49152, L + 49152,
            packPU + (size_t)(b < 2 ? (b+1)*65536 : 0),
            S, PU, b < 2);
    }
}